// Round 2
// baseline (700.180 us; speedup 1.0000x reference)
//
#include <hip/hip_runtime.h>
#include <hip/hip_bf16.h>

#define NN 100000
#define NE 1600000
#define DD 128
#define NG 8

__global__ void fill_zero(float* __restrict__ p, int n4) {
  int i = blockIdx.x * blockDim.x + threadIdx.x;
  if (i < n4) ((float4*)p)[i] = make_float4(0.f, 0.f, 0.f, 0.f);
}

__global__ void fill_zero_i(int* __restrict__ p, int n4) {
  int i = blockIdx.x * blockDim.x + threadIdx.x;
  if (i < n4) ((int4*)p)[i] = make_int4(0, 0, 0, 0);
}

__global__ void degrees_kernel(const int* __restrict__ src, const int* __restrict__ dst,
                               int* __restrict__ dout, int* __restrict__ din) {
  int e = blockIdx.x * blockDim.x + threadIdx.x;
  if (e < NE) {
    atomicAdd(&dout[src[e]], 1);
    atomicAdd(&din[dst[e]], 1);
  }
}

__global__ void rsqrt_deg_kernel(const int* __restrict__ dout, const int* __restrict__ din,
                                 float* __restrict__ rs_out, float* __restrict__ rs_in) {
  int i = blockIdx.x * blockDim.x + threadIdx.x;
  if (i < NN) {
    rs_out[i] = rsqrtf(fmaxf((float)dout[i], 1.f));
    rs_in[i]  = rsqrtf(fmaxf((float)din[i], 1.f));
  }
}

// ---- exclusive scan of deg_in (100000 ints) -> cursor (start offsets) ----
__global__ __launch_bounds__(256) void scan1_blocksum(const int* __restrict__ deg,
                                                      int* __restrict__ bsum) {
  __shared__ int sh[256];
  int t = threadIdx.x;
  int i = blockIdx.x * 256 + t;
  sh[t] = (i < NN) ? deg[i] : 0;
  __syncthreads();
  for (int off = 128; off >= 1; off >>= 1) {
    if (t < off) sh[t] += sh[t + off];
    __syncthreads();
  }
  if (t == 0) bsum[blockIdx.x] = sh[0];
}

__global__ __launch_bounds__(512) void scan2_prefix(const int* __restrict__ bsum,
                                                    int* __restrict__ bpref, int n) {
  __shared__ int sh[512];
  int t = threadIdx.x;
  int v = (t < n) ? bsum[t] : 0;
  sh[t] = v;
  __syncthreads();
  for (int off = 1; off < 512; off <<= 1) {
    int x = 0;
    if (t >= off) x = sh[t - off];
    __syncthreads();
    sh[t] += x;
    __syncthreads();
  }
  if (t < n) bpref[t] = sh[t] - v;  // exclusive
}

__global__ __launch_bounds__(256) void scan3_offsets(const int* __restrict__ deg,
                                                     const int* __restrict__ bpref,
                                                     int* __restrict__ cursor) {
  __shared__ int sh[256];
  int t = threadIdx.x;
  int i = blockIdx.x * 256 + t;
  int v = (i < NN) ? deg[i] : 0;
  sh[t] = v;
  __syncthreads();
  for (int off = 1; off < 256; off <<= 1) {
    int x = 0;
    if (t >= off) x = sh[t - off];
    __syncthreads();
    sh[t] += x;
    __syncthreads();
  }
  if (i < NN) cursor[i] = sh[t] - v + bpref[blockIdx.x];  // exclusive global offset
}

__global__ void csr_fill(const int* __restrict__ src, const int* __restrict__ dst,
                         int* __restrict__ cursor, int* __restrict__ csr_src) {
  int e = blockIdx.x * blockDim.x + threadIdx.x;
  if (e < NE) {
    int pos = atomicAdd(&cursor[dst[e]], 1);
    csr_src[pos] = src[e];
  }
}
// after csr_fill: cursor[d] == end offset of node d; start = end - deg_in[d]

// One 32-lane group per dst node; lane q covers floats 4q..4q+3.
__global__ __launch_bounds__(256) void gather_agg(
    const float* __restrict__ H, const int* __restrict__ csr_src,
    const int* __restrict__ cursor_end, const int* __restrict__ deg_in,
    const float* __restrict__ rs_out, float* __restrict__ agg) {
  int node = blockIdx.x * 8 + (threadIdx.x >> 5);
  if (node >= NN) return;
  int q = threadIdx.x & 31;
  int end = cursor_end[node];
  int beg = end - deg_in[node];
  float4 acc = make_float4(0.f, 0.f, 0.f, 0.f);
  for (int j = beg; j < end; ++j) {
    int s = csr_src[j];
    float w = rs_out[s];
    float4 v = *(const float4*)(H + (size_t)s * DD + q * 4);
    acc.x += v.x * w;
    acc.y += v.y * w;
    acc.z += v.z * w;
    acc.w += v.w * w;
  }
  *(float4*)(agg + (size_t)node * DD + q * 4) = acc;
}

// C[row] = relu((A[row] @ W) * rs[row] + bias), tile: 64 rows x 128 cols.
__global__ __launch_bounds__(256) void gemm_epilogue(
    const float* __restrict__ A, const float* __restrict__ W,
    const float* __restrict__ bias, const float* __restrict__ rs,
    float* __restrict__ C) {
  __shared__ float As[64][32];    // 8 KB
  __shared__ float Ws[32][128];   // 16 KB
  int tid = threadIdx.x;
  int row0 = blockIdx.x * 64;
  int cg = tid & 31;   // cols 4*cg .. 4*cg+3
  int rg = tid >> 5;   // rows rg*8 .. rg*8+7
  float4 acc[8];
#pragma unroll
  for (int r = 0; r < 8; ++r) acc[r] = make_float4(0.f, 0.f, 0.f, 0.f);

  for (int kk = 0; kk < DD; kk += 32) {
#pragma unroll
    for (int i = 0; i < 2; ++i) {
      int f = tid + i * 256;
      int arow = f >> 3;
      int acol = (f & 7) * 4;
      int grow = row0 + arow;
      float4 v = make_float4(0.f, 0.f, 0.f, 0.f);
      if (grow < NN) v = *(const float4*)&A[(size_t)grow * DD + kk + acol];
      *(float4*)&As[arow][acol] = v;
    }
#pragma unroll
    for (int i = 0; i < 4; ++i) {
      int f = tid + i * 256;
      int wrow = f >> 5;
      int wcol = (f & 31) * 4;
      *(float4*)&Ws[wrow][wcol] = *(const float4*)&W[(size_t)(kk + wrow) * DD + wcol];
    }
    __syncthreads();
#pragma unroll
    for (int k4 = 0; k4 < 8; ++k4) {
      float4 a4[8];
#pragma unroll
      for (int r = 0; r < 8; ++r) a4[r] = *(const float4*)&As[rg * 8 + r][k4 * 4];
#pragma unroll
      for (int j = 0; j < 4; ++j) {
        float4 w4 = *(const float4*)&Ws[k4 * 4 + j][cg * 4];
#pragma unroll
        for (int r = 0; r < 8; ++r) {
          float a = (j == 0) ? a4[r].x : (j == 1) ? a4[r].y : (j == 2) ? a4[r].z : a4[r].w;
          acc[r].x += a * w4.x;
          acc[r].y += a * w4.y;
          acc[r].z += a * w4.z;
          acc[r].w += a * w4.w;
        }
      }
    }
    __syncthreads();
  }
  float4 b4 = *(const float4*)&bias[cg * 4];
#pragma unroll
  for (int r = 0; r < 8; ++r) {
    int row = row0 + rg * 8 + r;
    if (row < NN) {
      float s = rs[row];
      float4 o;
      o.x = fmaxf(acc[r].x * s + b4.x, 0.f);
      o.y = fmaxf(acc[r].y * s + b4.y, 0.f);
      o.z = fmaxf(acc[r].z * s + b4.z, 0.f);
      o.w = fmaxf(acc[r].w * s + b4.w, 0.f);
      *(float4*)&C[(size_t)row * DD + cg * 4] = o;
    }
  }
}

// graph_ids sorted: per-block run accumulation, few atomics.
__global__ __launch_bounds__(128) void pool_kernel(const float* __restrict__ H,
                                                   const int* __restrict__ gid,
                                                   float* __restrict__ pooled,
                                                   float* __restrict__ cnt) {
  __shared__ int gs[256];
  int t = threadIdx.x;
  int n0 = blockIdx.x * 256;
  int nn = NN - n0;
  if (nn > 256) nn = 256;
  if (nn <= 0) return;
  for (int i = t; i < nn; i += 128) gs[i] = gid[n0 + i];
  __syncthreads();
  int curg = gs[0];
  float acc = 0.f;
  float c = 0.f;
  for (int i = 0; i < nn; ++i) {
    int g = gs[i];
    if (g != curg) {
      atomicAdd(&pooled[curg * DD + t], acc);
      if (t == 0) atomicAdd(&cnt[curg], c);
      acc = 0.f;
      c = 0.f;
      curg = g;
    }
    acc += H[(size_t)(n0 + i) * DD + t];
    c += 1.f;
  }
  atomicAdd(&pooled[curg * DD + t], acc);
  if (t == 0) atomicAdd(&cnt[curg], c);
}

__global__ __launch_bounds__(128) void final_kernel(const float* __restrict__ pooled,
                                                    const float* __restrict__ cnt,
                                                    const float* __restrict__ prelu_a,
                                                    const float* __restrict__ linW,
                                                    const float* __restrict__ linb,
                                                    float* __restrict__ out) {
  int t = threadIdx.x;  // 128
  __shared__ float red[2];
  float w = linW[t];
  float alpha = prelu_a[0];
  float lb = linb[0];
  for (int g = 0; g < NG; ++g) {
    float v = pooled[g * DD + t] / fmaxf(cnt[g], 1.f);
    v = v > 0.f ? v : alpha * v;
    float p = v * w;
#pragma unroll
    for (int off = 32; off >= 1; off >>= 1) p += __shfl_down(p, off, 64);
    if ((t & 63) == 0) red[t >> 6] = p;
    __syncthreads();
    if (t == 0) {
      float s = red[0] + red[1] + lb;
      out[g] = 1.f / (1.f + expf(-s));
    }
    __syncthreads();
  }
}

extern "C" void kernel_launch(void* const* d_in, const int* in_sizes, int n_in,
                              void* d_out, int out_size, void* d_ws, size_t ws_size,
                              hipStream_t stream) {
  const float* x   = (const float*)d_in[0];
  const int*   src = (const int*)d_in[1];
  const int*   dst = (const int*)d_in[2];
  const int*   gid = (const int*)d_in[3];
  const float* W1  = (const float*)d_in[4];
  const float* b1  = (const float*)d_in[5];
  const float* W2  = (const float*)d_in[6];
  const float* b2  = (const float*)d_in[7];
  const float* pa  = (const float*)d_in[8];
  const float* lW  = (const float*)d_in[9];
  const float* lb  = (const float*)d_in[10];
  float* out = (float*)d_out;

  char* ws = (char*)d_ws;
  size_t o = 0;
  auto alloc = [&](size_t bytes) {
    size_t r = o;
    o += (bytes + 255) & ~(size_t)255;
    return r;
  };
  int*   deg_out = (int*)(ws + alloc((size_t)NN * 4));
  int*   deg_in  = (int*)(ws + alloc((size_t)NN * 4));
  float* rs_out  = (float*)(ws + alloc((size_t)NN * 4));
  float* rs_in   = (float*)(ws + alloc((size_t)NN * 4));
  int*   bsum    = (int*)(ws + alloc(512 * 4));
  int*   bpref   = (int*)(ws + alloc(512 * 4));
  int*   cursor  = (int*)(ws + alloc((size_t)NN * 4));
  int*   csr_src = (int*)(ws + alloc((size_t)NE * 4));
  float* aggbuf  = (float*)(ws + alloc((size_t)NN * DD * 4));
  float* hbuf    = (float*)(ws + alloc((size_t)NN * DD * 4));
  float* pooled  = (float*)(ws + alloc((size_t)(NG * DD + NG) * 4));
  float* cnt     = pooled + NG * DD;

  const int nblk = (NN + 255) / 256;  // 391

  // zero degree histograms + pooled/cnt (258 float4s -> 2 blocks!)
  fill_zero_i<<<(NN / 4 + 255) / 256, 256, 0, stream>>>(deg_out, NN / 4);
  fill_zero_i<<<(NN / 4 + 255) / 256, 256, 0, stream>>>(deg_in, NN / 4);
  fill_zero<<<2, 256, 0, stream>>>(pooled, (NG * DD + NG + 3) / 4);

  degrees_kernel<<<(NE + 255) / 256, 256, 0, stream>>>(src, dst, deg_out, deg_in);
  rsqrt_deg_kernel<<<nblk, 256, 0, stream>>>(deg_out, deg_in, rs_out, rs_in);

  // CSR by dst
  scan1_blocksum<<<nblk, 256, 0, stream>>>(deg_in, bsum);
  scan2_prefix<<<1, 512, 0, stream>>>(bsum, bpref, nblk);
  scan3_offsets<<<nblk, 256, 0, stream>>>(deg_in, bpref, cursor);
  csr_fill<<<(NE + 255) / 256, 256, 0, stream>>>(src, dst, cursor, csr_src);

  const int gablocks = (NN + 7) / 8;   // 12500
  const int gmblocks = (NN + 63) / 64; // 1563

  // Layer 1
  gather_agg<<<gablocks, 256, 0, stream>>>(x, csr_src, cursor, deg_in, rs_out, aggbuf);
  gemm_epilogue<<<gmblocks, 256, 0, stream>>>(aggbuf, W1, b1, rs_in, hbuf);

  // Layer 2
  gather_agg<<<gablocks, 256, 0, stream>>>(hbuf, csr_src, cursor, deg_in, rs_out, aggbuf);
  gemm_epilogue<<<gmblocks, 256, 0, stream>>>(aggbuf, W2, b2, rs_in, hbuf);

  // Pool + head
  pool_kernel<<<nblk, 128, 0, stream>>>(hbuf, gid, pooled, cnt);
  final_kernel<<<1, 128, 0, stream>>>(pooled, cnt, pa, lW, lb, out);
}

// Round 3
// 635.969 us; speedup vs baseline: 1.1010x; 1.1010x over previous
//
#include <hip/hip_runtime.h>
#include <hip/hip_bf16.h>

#define NN 100000
#define NE 1600000
#define DD 128
#define NG 8

typedef unsigned short u16;
typedef __attribute__((ext_vector_type(8))) short short8;
typedef __attribute__((ext_vector_type(4))) float f32x4;

static __device__ __forceinline__ float bf2f(u16 u) {
  return __uint_as_float(((unsigned)u) << 16);
}
static __device__ __forceinline__ u16 f2bf(float f) {
  unsigned u = __float_as_uint(f);
  u += 0x7fffu + ((u >> 16) & 1);   // round-to-nearest-even
  return (u16)(u >> 16);
}

__global__ void fill_zero(float* __restrict__ p, int n4) {
  int i = blockIdx.x * blockDim.x + threadIdx.x;
  if (i < n4) ((float4*)p)[i] = make_float4(0.f, 0.f, 0.f, 0.f);
}

__global__ void fill_zero_i(int* __restrict__ p, int n4) {
  int i = blockIdx.x * blockDim.x + threadIdx.x;
  if (i < n4) ((int4*)p)[i] = make_int4(0, 0, 0, 0);
}

__global__ void conv_f32_to_bf16(const float* __restrict__ in, u16* __restrict__ out, int n8) {
  int i = blockIdx.x * blockDim.x + threadIdx.x;
  if (i >= n8) return;
  const float4* p = (const float4*)(in + (size_t)i * 8);
  float4 a = p[0], b = p[1];
  uint4 v;
  v.x = (unsigned)f2bf(a.x) | ((unsigned)f2bf(a.y) << 16);
  v.y = (unsigned)f2bf(a.z) | ((unsigned)f2bf(a.w) << 16);
  v.z = (unsigned)f2bf(b.x) | ((unsigned)f2bf(b.y) << 16);
  v.w = (unsigned)f2bf(b.z) | ((unsigned)f2bf(b.w) << 16);
  *(uint4*)(out + (size_t)i * 8) = v;
}

// Wt[n][k] = W[k][n], bf16. 16384 elems.
__global__ void conv_w_transpose(const float* __restrict__ W, u16* __restrict__ Wt) {
  int idx = blockIdx.x * blockDim.x + threadIdx.x;
  if (idx >= DD * DD) return;
  int n = idx >> 7, k = idx & 127;
  Wt[idx] = f2bf(W[k * DD + n]);
}

__global__ void degrees_kernel(const int* __restrict__ src, const int* __restrict__ dst,
                               int* __restrict__ dout, int* __restrict__ din) {
  int e = blockIdx.x * blockDim.x + threadIdx.x;
  if (e < NE) {
    atomicAdd(&dout[src[e]], 1);
    atomicAdd(&din[dst[e]], 1);
  }
}

__global__ void rsqrt_deg_kernel(const int* __restrict__ dout, const int* __restrict__ din,
                                 float* __restrict__ rs_out, float* __restrict__ rs_in) {
  int i = blockIdx.x * blockDim.x + threadIdx.x;
  if (i < NN) {
    rs_out[i] = rsqrtf(fmaxf((float)dout[i], 1.f));
    rs_in[i]  = rsqrtf(fmaxf((float)din[i], 1.f));
  }
}

// ---- exclusive scan of deg_in -> cursor (start offsets) ----
__global__ __launch_bounds__(256) void scan1_blocksum(const int* __restrict__ deg,
                                                      int* __restrict__ bsum) {
  __shared__ int sh[256];
  int t = threadIdx.x;
  int i = blockIdx.x * 256 + t;
  sh[t] = (i < NN) ? deg[i] : 0;
  __syncthreads();
  for (int off = 128; off >= 1; off >>= 1) {
    if (t < off) sh[t] += sh[t + off];
    __syncthreads();
  }
  if (t == 0) bsum[blockIdx.x] = sh[0];
}

__global__ __launch_bounds__(512) void scan2_prefix(const int* __restrict__ bsum,
                                                    int* __restrict__ bpref, int n) {
  __shared__ int sh[512];
  int t = threadIdx.x;
  int v = (t < n) ? bsum[t] : 0;
  sh[t] = v;
  __syncthreads();
  for (int off = 1; off < 512; off <<= 1) {
    int x = 0;
    if (t >= off) x = sh[t - off];
    __syncthreads();
    sh[t] += x;
    __syncthreads();
  }
  if (t < n) bpref[t] = sh[t] - v;
}

__global__ __launch_bounds__(256) void scan3_offsets(const int* __restrict__ deg,
                                                     const int* __restrict__ bpref,
                                                     int* __restrict__ cursor) {
  __shared__ int sh[256];
  int t = threadIdx.x;
  int i = blockIdx.x * 256 + t;
  int v = (i < NN) ? deg[i] : 0;
  sh[t] = v;
  __syncthreads();
  for (int off = 1; off < 256; off <<= 1) {
    int x = 0;
    if (t >= off) x = sh[t - off];
    __syncthreads();
    sh[t] += x;
    __syncthreads();
  }
  if (i < NN) cursor[i] = sh[t] - v + bpref[blockIdx.x];
}

__global__ void csr_fill(const int* __restrict__ src, const int* __restrict__ dst,
                         int* __restrict__ cursor, int* __restrict__ csr_src) {
  int e = blockIdx.x * blockDim.x + threadIdx.x;
  if (e < NE) {
    int pos = atomicAdd(&cursor[dst[e]], 1);
    csr_src[pos] = src[e];
  }
}
// after csr_fill: cursor[d] == end offset of node d

// One 32-lane group per dst node; lane q covers bf16 elems 4q..4q+3 (8B).
__global__ __launch_bounds__(256) void gather_agg_bf16(
    const u16* __restrict__ H, const int* __restrict__ csr_src,
    const int* __restrict__ cursor_end, const int* __restrict__ deg_in,
    const float* __restrict__ rs_out, u16* __restrict__ agg) {
  int node = blockIdx.x * 8 + (threadIdx.x >> 5);
  if (node >= NN) return;
  int q = threadIdx.x & 31;
  int end = cursor_end[node];
  int beg = end - deg_in[node];
  float a0 = 0.f, a1 = 0.f, a2 = 0.f, a3 = 0.f;
  for (int j = beg; j < end; ++j) {
    int s = csr_src[j];
    float w = rs_out[s];
    ushort4 v = *(const ushort4*)(H + (size_t)s * DD + q * 4);
    a0 += bf2f(v.x) * w;
    a1 += bf2f(v.y) * w;
    a2 += bf2f(v.z) * w;
    a3 += bf2f(v.w) * w;
  }
  uint2 o;
  o.x = (unsigned)f2bf(a0) | ((unsigned)f2bf(a1) << 16);
  o.y = (unsigned)f2bf(a2) | ((unsigned)f2bf(a3) << 16);
  *(uint2*)(agg + (size_t)node * DD + q * 4) = o;
}

// C[r][c] = relu((A@W)[r][c] * rs[r] + bias[c]) in bf16.
// A: [NN][128] bf16 row-major. Wt: [128][128] bf16 with Wt[n][k]=W[k][n].
// Block = 4 waves, wave w owns rows row0..row0+15; 8 col-tiles of 16; K=128 in 4 steps of 32.
__global__ __launch_bounds__(256) void gemm_mfma(
    const u16* __restrict__ Ab, const u16* __restrict__ Wt,
    const float* __restrict__ bias, const float* __restrict__ rs,
    u16* __restrict__ Cb) {
  int wid = threadIdx.x >> 6;
  int lane = threadIdx.x & 63;
  int row0 = blockIdx.x * 64 + wid * 16;
  int l15 = lane & 15;
  int kg = lane >> 4;                 // k-block: elems kg*8..kg*8+7 of each 32-slice
  int arow = row0 + l15;
  bool rowok = arow < NN;
  const u16* aptr = Ab + (size_t)arow * DD + kg * 8;
  const u16* bbase = Wt + (size_t)l15 * DD + kg * 8;
  f32x4 acc[8];
#pragma unroll
  for (int n = 0; n < 8; ++n) acc[n] = (f32x4){0.f, 0.f, 0.f, 0.f};
#pragma unroll
  for (int kt = 0; kt < 4; ++kt) {
    short8 a = (short8){0, 0, 0, 0, 0, 0, 0, 0};
    if (rowok) a = *(const short8*)(aptr + kt * 32);
#pragma unroll
    for (int n = 0; n < 8; ++n) {
      short8 b = *(const short8*)(bbase + (size_t)n * 16 * DD + kt * 32);
      acc[n] = __builtin_amdgcn_mfma_f32_16x16x32_bf16(a, b, acc[n], 0, 0, 0);
    }
  }
  // D[row=(lane>>4)*4+j][col=n*16+(lane&15)]
  int crow0 = row0 + kg * 4;
#pragma unroll
  for (int j = 0; j < 4; ++j) {
    int r = crow0 + j;
    if (r < NN) {
      float s = rs[r];
#pragma unroll
      for (int n = 0; n < 8; ++n) {
        float v = fmaxf(acc[n][j] * s + bias[n * 16 + l15], 0.f);
        Cb[(size_t)r * DD + n * 16 + l15] = f2bf(v);
      }
    }
  }
}

// graph_ids sorted: per-block run accumulation, few atomics. H is bf16.
__global__ __launch_bounds__(128) void pool_kernel(const u16* __restrict__ H,
                                                   const int* __restrict__ gid,
                                                   float* __restrict__ pooled,
                                                   float* __restrict__ cnt) {
  __shared__ int gs[256];
  int t = threadIdx.x;
  int n0 = blockIdx.x * 256;
  int nn = NN - n0;
  if (nn > 256) nn = 256;
  if (nn <= 0) return;
  for (int i = t; i < nn; i += 128) gs[i] = gid[n0 + i];
  __syncthreads();
  int curg = gs[0];
  float acc = 0.f;
  float c = 0.f;
  for (int i = 0; i < nn; ++i) {
    int g = gs[i];
    if (g != curg) {
      atomicAdd(&pooled[curg * DD + t], acc);
      if (t == 0) atomicAdd(&cnt[curg], c);
      acc = 0.f;
      c = 0.f;
      curg = g;
    }
    acc += bf2f(H[(size_t)(n0 + i) * DD + t]);
    c += 1.f;
  }
  atomicAdd(&pooled[curg * DD + t], acc);
  if (t == 0) atomicAdd(&cnt[curg], c);
}

__global__ __launch_bounds__(128) void final_kernel(const float* __restrict__ pooled,
                                                    const float* __restrict__ cnt,
                                                    const float* __restrict__ prelu_a,
                                                    const float* __restrict__ linW,
                                                    const float* __restrict__ linb,
                                                    float* __restrict__ out) {
  int t = threadIdx.x;  // 128
  __shared__ float red[2];
  float w = linW[t];
  float alpha = prelu_a[0];
  float lb = linb[0];
  for (int g = 0; g < NG; ++g) {
    float v = pooled[g * DD + t] / fmaxf(cnt[g], 1.f);
    v = v > 0.f ? v : alpha * v;
    float p = v * w;
#pragma unroll
    for (int off = 32; off >= 1; off >>= 1) p += __shfl_down(p, off, 64);
    if ((t & 63) == 0) red[t >> 6] = p;
    __syncthreads();
    if (t == 0) {
      float s = red[0] + red[1] + lb;
      out[g] = 1.f / (1.f + expf(-s));
    }
    __syncthreads();
  }
}

extern "C" void kernel_launch(void* const* d_in, const int* in_sizes, int n_in,
                              void* d_out, int out_size, void* d_ws, size_t ws_size,
                              hipStream_t stream) {
  const float* x   = (const float*)d_in[0];
  const int*   src = (const int*)d_in[1];
  const int*   dst = (const int*)d_in[2];
  const int*   gid = (const int*)d_in[3];
  const float* W1  = (const float*)d_in[4];
  const float* b1  = (const float*)d_in[5];
  const float* W2  = (const float*)d_in[6];
  const float* b2  = (const float*)d_in[7];
  const float* pa  = (const float*)d_in[8];
  const float* lW  = (const float*)d_in[9];
  const float* lb  = (const float*)d_in[10];
  float* out = (float*)d_out;

  char* ws = (char*)d_ws;
  size_t o = 0;
  auto alloc = [&](size_t bytes) {
    size_t r = o;
    o += (bytes + 255) & ~(size_t)255;
    return r;
  };
  int*   deg_out = (int*)(ws + alloc((size_t)NN * 4));
  int*   deg_in  = (int*)(ws + alloc((size_t)NN * 4));
  float* rs_out  = (float*)(ws + alloc((size_t)NN * 4));
  float* rs_in   = (float*)(ws + alloc((size_t)NN * 4));
  int*   bsum    = (int*)(ws + alloc(512 * 4));
  int*   bpref   = (int*)(ws + alloc(512 * 4));
  int*   cursor  = (int*)(ws + alloc((size_t)NN * 4));
  int*   csr_src = (int*)(ws + alloc((size_t)NE * 4));
  u16*   Wt1     = (u16*)(ws + alloc((size_t)DD * DD * 2));
  u16*   Wt2     = (u16*)(ws + alloc((size_t)DD * DD * 2));
  u16*   buf1    = (u16*)(ws + alloc((size_t)NN * DD * 2));
  u16*   buf2    = (u16*)(ws + alloc((size_t)NN * DD * 2));
  u16*   buf3    = (u16*)(ws + alloc((size_t)NN * DD * 2));
  float* pooled  = (float*)(ws + alloc((size_t)(NG * DD + NG) * 4));
  float* cnt     = pooled + NG * DD;

  const int nblk = (NN + 255) / 256;  // 391

  fill_zero_i<<<(NN / 4 + 255) / 256, 256, 0, stream>>>(deg_out, NN / 4);
  fill_zero_i<<<(NN / 4 + 255) / 256, 256, 0, stream>>>(deg_in, NN / 4);
  fill_zero<<<2, 256, 0, stream>>>(pooled, (NG * DD + NG + 3) / 4);

  conv_f32_to_bf16<<<(NN * DD / 8 + 255) / 256, 256, 0, stream>>>(x, buf1, NN * DD / 8);
  conv_w_transpose<<<64, 256, 0, stream>>>(W1, Wt1);
  conv_w_transpose<<<64, 256, 0, stream>>>(W2, Wt2);

  degrees_kernel<<<(NE + 255) / 256, 256, 0, stream>>>(src, dst, deg_out, deg_in);
  rsqrt_deg_kernel<<<nblk, 256, 0, stream>>>(deg_out, deg_in, rs_out, rs_in);

  scan1_blocksum<<<nblk, 256, 0, stream>>>(deg_in, bsum);
  scan2_prefix<<<1, 512, 0, stream>>>(bsum, bpref, nblk);
  scan3_offsets<<<nblk, 256, 0, stream>>>(deg_in, bpref, cursor);
  csr_fill<<<(NE + 255) / 256, 256, 0, stream>>>(src, dst, cursor, csr_src);

  const int gablocks = (NN + 7) / 8;   // 12500
  const int gmblocks = (NN + 63) / 64; // 1563

  // Layer 1
  gather_agg_bf16<<<gablocks, 256, 0, stream>>>(buf1, csr_src, cursor, deg_in, rs_out, buf2);
  gemm_mfma<<<gmblocks, 256, 0, stream>>>(buf2, Wt1, b1, rs_in, buf3);

  // Layer 2 (reuse buf1, buf2)
  gather_agg_bf16<<<gablocks, 256, 0, stream>>>(buf3, csr_src, cursor, deg_in, rs_out, buf1);
  gemm_mfma<<<gmblocks, 256, 0, stream>>>(buf1, Wt2, b2, rs_in, buf2);

  // Pool + head
  pool_kernel<<<nblk, 128, 0, stream>>>(buf2, gid, pooled, cnt);
  final_kernel<<<1, 128, 0, stream>>>(pooled, cnt, pa, lW, lb, out);
}

// Round 4
// 516.218 us; speedup vs baseline: 1.3564x; 1.2320x over previous
//
#include <hip/hip_runtime.h>
#include <hip/hip_bf16.h>

#define NN 100000
#define NE 1600000
#define DD 128
#define NG 8

#define KB 98        // dst buckets (dst >> 10)
#define BSH 10
#define PB 128       // phase-1/2 blocks
#define CHUNK 12500  // NE / PB exactly
#define SCAN_N (KB * PB)  // 12544

typedef unsigned short u16;
typedef __attribute__((ext_vector_type(8))) short short8;
typedef __attribute__((ext_vector_type(4))) float f32x4;

static __device__ __forceinline__ float bf2f(u16 u) {
  return __uint_as_float(((unsigned)u) << 16);
}
static __device__ __forceinline__ u16 f2bf(float f) {
  unsigned u = __float_as_uint(f);
  u += 0x7fffu + ((u >> 16) & 1);
  return (u16)(u >> 16);
}

__global__ void fill_zero(float* __restrict__ p, int n4) {
  int i = blockIdx.x * blockDim.x + threadIdx.x;
  if (i < n4) ((float4*)p)[i] = make_float4(0.f, 0.f, 0.f, 0.f);
}

__global__ void fill_zero_i(int* __restrict__ p, int n4) {
  int i = blockIdx.x * blockDim.x + threadIdx.x;
  if (i < n4) ((int4*)p)[i] = make_int4(0, 0, 0, 0);
}

__global__ void conv_f32_to_bf16(const float* __restrict__ in, u16* __restrict__ out, int n8) {
  int i = blockIdx.x * blockDim.x + threadIdx.x;
  if (i >= n8) return;
  const float4* p = (const float4*)(in + (size_t)i * 8);
  float4 a = p[0], b = p[1];
  uint4 v;
  v.x = (unsigned)f2bf(a.x) | ((unsigned)f2bf(a.y) << 16);
  v.y = (unsigned)f2bf(a.z) | ((unsigned)f2bf(a.w) << 16);
  v.z = (unsigned)f2bf(b.x) | ((unsigned)f2bf(b.y) << 16);
  v.w = (unsigned)f2bf(b.z) | ((unsigned)f2bf(b.w) << 16);
  *(uint4*)(out + (size_t)i * 8) = v;
}

__global__ void conv_w_transpose(const float* __restrict__ W, u16* __restrict__ Wt) {
  int idx = blockIdx.x * blockDim.x + threadIdx.x;
  if (idx >= DD * DD) return;
  int n = idx >> 7, k = idx & 127;
  Wt[idx] = f2bf(W[k * DD + n]);
}

__global__ void deg_out_kernel(const int* __restrict__ src, int* __restrict__ dout) {
  int e = blockIdx.x * blockDim.x + threadIdx.x;
  if (e < NE) atomicAdd(&dout[src[e]], 1);
}

__global__ void rs_out_kernel(const int* __restrict__ dout, float* __restrict__ rs_out) {
  int i = blockIdx.x * blockDim.x + threadIdx.x;
  if (i < NN) rs_out[i] = rsqrtf(fmaxf((float)dout[i], 1.f));
}

// ---- CSR build: two-level counting sort ----
__global__ __launch_bounds__(256) void csr_p1(const int* __restrict__ dst,
                                              int* __restrict__ counts) {
  __shared__ int hist[KB];
  int t = threadIdx.x, blk = blockIdx.x;
  for (int i = t; i < KB; i += 256) hist[i] = 0;
  __syncthreads();
  int e0 = blk * CHUNK;
  for (int i = t; i < CHUNK; i += 256) atomicAdd(&hist[dst[e0 + i] >> BSH], 1);
  __syncthreads();
  for (int i = t; i < KB; i += 256) counts[i * PB + blk] = hist[i];
}

__global__ __launch_bounds__(256) void csr_scan(int* __restrict__ counts) {
  __shared__ int data[SCAN_N];   // 50 KB
  __shared__ int part[256];
  int t = threadIdx.x;
  const int per = (SCAN_N + 255) / 256;  // 49
  for (int i = t; i < SCAN_N; i += 256) data[i] = counts[i];
  __syncthreads();
  int base = t * per;
  int s = 0;
  for (int i = 0; i < per; ++i) {
    int idx = base + i;
    if (idx < SCAN_N) s += data[idx];
  }
  part[t] = s;
  __syncthreads();
  for (int off = 1; off < 256; off <<= 1) {
    int v = (t >= off) ? part[t - off] : 0;
    __syncthreads();
    part[t] += v;
    __syncthreads();
  }
  int run = (t == 0) ? 0 : part[t - 1];
  for (int i = 0; i < per; ++i) {
    int idx = base + i;
    if (idx < SCAN_N) {
      int v = data[idx];
      data[idx] = run;
      run += v;
    }
  }
  __syncthreads();
  for (int i = t; i < SCAN_N; i += 256) counts[i] = data[i];
}

__global__ __launch_bounds__(256) void csr_p2(const int* __restrict__ src,
                                              const int* __restrict__ dst,
                                              const int* __restrict__ scanned,
                                              unsigned* __restrict__ recs) {
  __shared__ int cur[KB];
  int t = threadIdx.x, blk = blockIdx.x;
  for (int i = t; i < KB; i += 256) cur[i] = scanned[i * PB + blk];
  __syncthreads();
  int e0 = blk * CHUNK;
  for (int i = t; i < CHUNK; i += 256) {
    int s = src[e0 + i];
    int d = dst[e0 + i];
    int k = d >> BSH;
    int pos = atomicAdd(&cur[k], 1);
    recs[pos] = (unsigned)s | ((unsigned)(d & ((1 << BSH) - 1)) << 17);
  }
}

// One block per bucket: per-node degree, offsets, deg_in/rs_in/cursor_end, csr scatter.
__global__ __launch_bounds__(256) void csr_p3(const unsigned* __restrict__ recs,
                                              const int* __restrict__ scanned,
                                              int* __restrict__ csr_src,
                                              int* __restrict__ cursor_end,
                                              int* __restrict__ deg_in,
                                              float* __restrict__ rs_in) {
  __shared__ int hist[1 << BSH];  // 1024
  __shared__ int part[256];
  int k = blockIdx.x, t = threadIdx.x;
  int rbeg = scanned[k * PB];
  int rend = (k < KB - 1) ? scanned[(k + 1) * PB] : NE;
  int nbase = k << BSH;
  for (int i = t; i < (1 << BSH); i += 256) hist[i] = 0;
  __syncthreads();
  for (int i = rbeg + t; i < rend; i += 256) atomicAdd(&hist[recs[i] >> 17], 1);
  __syncthreads();
  int h[4];
#pragma unroll
  for (int j = 0; j < 4; ++j) h[j] = hist[t * 4 + j];
  part[t] = h[0] + h[1] + h[2] + h[3];
  __syncthreads();
  for (int off = 1; off < 256; off <<= 1) {
    int v = (t >= off) ? part[t - off] : 0;
    __syncthreads();
    part[t] += v;
    __syncthreads();
  }
  int run = rbeg + ((t == 0) ? 0 : part[t - 1]);
#pragma unroll
  for (int j = 0; j < 4; ++j) {
    int n = nbase + t * 4 + j;
    if (n < NN) {
      cursor_end[n] = run + h[j];
      deg_in[n] = h[j];
      rs_in[n] = rsqrtf(fmaxf((float)h[j], 1.f));
    }
    hist[t * 4 + j] = run;   // running write cursor (start)
    run += h[j];
  }
  __syncthreads();
  for (int i = rbeg + t; i < rend; i += 256) {
    unsigned r = recs[i];
    int pos = atomicAdd(&hist[r >> 17], 1);
    csr_src[pos] = (int)(r & 0x1FFFF);
  }
}

// One 32-lane group per dst node; lane q covers bf16 elems 4q..4q+3 (8B).
__global__ __launch_bounds__(256) void gather_agg_bf16(
    const u16* __restrict__ H, const int* __restrict__ csr_src,
    const int* __restrict__ cursor_end, const int* __restrict__ deg_in,
    const float* __restrict__ rs_out, u16* __restrict__ agg) {
  int node = blockIdx.x * 8 + (threadIdx.x >> 5);
  if (node >= NN) return;
  int q = threadIdx.x & 31;
  int end = cursor_end[node];
  int beg = end - deg_in[node];
  float a0 = 0.f, a1 = 0.f, a2 = 0.f, a3 = 0.f;
  for (int j = beg; j < end; ++j) {
    int s = csr_src[j];
    float w = rs_out[s];
    ushort4 v = *(const ushort4*)(H + (size_t)s * DD + q * 4);
    a0 += bf2f(v.x) * w;
    a1 += bf2f(v.y) * w;
    a2 += bf2f(v.z) * w;
    a3 += bf2f(v.w) * w;
  }
  uint2 o;
  o.x = (unsigned)f2bf(a0) | ((unsigned)f2bf(a1) << 16);
  o.y = (unsigned)f2bf(a2) | ((unsigned)f2bf(a3) << 16);
  *(uint2*)(agg + (size_t)node * DD + q * 4) = o;
}

// C[r][c] = relu((A@W)[r][c] * rs[r] + bias[c]) in bf16. Wt[n][k]=W[k][n].
__global__ __launch_bounds__(256) void gemm_mfma(
    const u16* __restrict__ Ab, const u16* __restrict__ Wt,
    const float* __restrict__ bias, const float* __restrict__ rs,
    u16* __restrict__ Cb) {
  int wid = threadIdx.x >> 6;
  int lane = threadIdx.x & 63;
  int row0 = blockIdx.x * 64 + wid * 16;
  int l15 = lane & 15;
  int kg = lane >> 4;
  int arow = row0 + l15;
  bool rowok = arow < NN;
  const u16* aptr = Ab + (size_t)arow * DD + kg * 8;
  const u16* bbase = Wt + (size_t)l15 * DD + kg * 8;
  f32x4 acc[8];
#pragma unroll
  for (int n = 0; n < 8; ++n) acc[n] = (f32x4){0.f, 0.f, 0.f, 0.f};
#pragma unroll
  for (int kt = 0; kt < 4; ++kt) {
    short8 a = (short8){0, 0, 0, 0, 0, 0, 0, 0};
    if (rowok) a = *(const short8*)(aptr + kt * 32);
#pragma unroll
    for (int n = 0; n < 8; ++n) {
      short8 b = *(const short8*)(bbase + (size_t)n * 16 * DD + kt * 32);
      acc[n] = __builtin_amdgcn_mfma_f32_16x16x32_bf16(a, b, acc[n], 0, 0, 0);
    }
  }
  int crow0 = row0 + kg * 4;
#pragma unroll
  for (int j = 0; j < 4; ++j) {
    int r = crow0 + j;
    if (r < NN) {
      float s = rs[r];
#pragma unroll
      for (int n = 0; n < 8; ++n) {
        float v = fmaxf(acc[n][j] * s + bias[n * 16 + l15], 0.f);
        Cb[(size_t)r * DD + n * 16 + l15] = f2bf(v);
      }
    }
  }
}

__global__ __launch_bounds__(128) void pool_kernel(const u16* __restrict__ H,
                                                   const int* __restrict__ gid,
                                                   float* __restrict__ pooled,
                                                   float* __restrict__ cnt) {
  __shared__ int gs[256];
  int t = threadIdx.x;
  int n0 = blockIdx.x * 256;
  int nn = NN - n0;
  if (nn > 256) nn = 256;
  if (nn <= 0) return;
  for (int i = t; i < nn; i += 128) gs[i] = gid[n0 + i];
  __syncthreads();
  int curg = gs[0];
  float acc = 0.f;
  float c = 0.f;
  for (int i = 0; i < nn; ++i) {
    int g = gs[i];
    if (g != curg) {
      atomicAdd(&pooled[curg * DD + t], acc);
      if (t == 0) atomicAdd(&cnt[curg], c);
      acc = 0.f;
      c = 0.f;
      curg = g;
    }
    acc += bf2f(H[(size_t)(n0 + i) * DD + t]);
    c += 1.f;
  }
  atomicAdd(&pooled[curg * DD + t], acc);
  if (t == 0) atomicAdd(&cnt[curg], c);
}

__global__ __launch_bounds__(128) void final_kernel(const float* __restrict__ pooled,
                                                    const float* __restrict__ cnt,
                                                    const float* __restrict__ prelu_a,
                                                    const float* __restrict__ linW,
                                                    const float* __restrict__ linb,
                                                    float* __restrict__ out) {
  int t = threadIdx.x;  // 128
  __shared__ float red[2];
  float w = linW[t];
  float alpha = prelu_a[0];
  float lb = linb[0];
  for (int g = 0; g < NG; ++g) {
    float v = pooled[g * DD + t] / fmaxf(cnt[g], 1.f);
    v = v > 0.f ? v : alpha * v;
    float p = v * w;
#pragma unroll
    for (int off = 32; off >= 1; off >>= 1) p += __shfl_down(p, off, 64);
    if ((t & 63) == 0) red[t >> 6] = p;
    __syncthreads();
    if (t == 0) {
      float s = red[0] + red[1] + lb;
      out[g] = 1.f / (1.f + expf(-s));
    }
    __syncthreads();
  }
}

extern "C" void kernel_launch(void* const* d_in, const int* in_sizes, int n_in,
                              void* d_out, int out_size, void* d_ws, size_t ws_size,
                              hipStream_t stream) {
  const float* x   = (const float*)d_in[0];
  const int*   src = (const int*)d_in[1];
  const int*   dst = (const int*)d_in[2];
  const int*   gid = (const int*)d_in[3];
  const float* W1  = (const float*)d_in[4];
  const float* b1  = (const float*)d_in[5];
  const float* W2  = (const float*)d_in[6];
  const float* b2  = (const float*)d_in[7];
  const float* pa  = (const float*)d_in[8];
  const float* lW  = (const float*)d_in[9];
  const float* lb  = (const float*)d_in[10];
  float* out = (float*)d_out;

  char* ws = (char*)d_ws;
  size_t o = 0;
  auto alloc = [&](size_t bytes) {
    size_t r = o;
    o += (bytes + 255) & ~(size_t)255;
    return r;
  };
  int*   deg_out = (int*)(ws + alloc((size_t)NN * 4));
  int*   deg_in  = (int*)(ws + alloc((size_t)NN * 4));
  float* rs_out  = (float*)(ws + alloc((size_t)NN * 4));
  float* rs_in   = (float*)(ws + alloc((size_t)NN * 4));
  int*   counts  = (int*)(ws + alloc((size_t)SCAN_N * 4));
  int*   cursor_end = (int*)(ws + alloc((size_t)NN * 4));
  unsigned* recs = (unsigned*)(ws + alloc((size_t)NE * 4));
  int*   csr_src = (int*)(ws + alloc((size_t)NE * 4));
  u16*   Wt1     = (u16*)(ws + alloc((size_t)DD * DD * 2));
  u16*   Wt2     = (u16*)(ws + alloc((size_t)DD * DD * 2));
  u16*   buf1    = (u16*)(ws + alloc((size_t)NN * DD * 2));
  u16*   buf2    = (u16*)(ws + alloc((size_t)NN * DD * 2));
  u16*   buf3    = (u16*)(ws + alloc((size_t)NN * DD * 2));
  float* pooled  = (float*)(ws + alloc((size_t)(NG * DD + NG) * 4));
  float* cnt     = pooled + NG * DD;

  const int nblk = (NN + 255) / 256;  // 391

  fill_zero_i<<<(NN / 4 + 255) / 256, 256, 0, stream>>>(deg_out, NN / 4);
  fill_zero<<<2, 256, 0, stream>>>(pooled, (NG * DD + NG + 3) / 4);

  conv_f32_to_bf16<<<(NN * DD / 8 + 255) / 256, 256, 0, stream>>>(x, buf1, NN * DD / 8);
  conv_w_transpose<<<64, 256, 0, stream>>>(W1, Wt1);
  conv_w_transpose<<<64, 256, 0, stream>>>(W2, Wt2);

  deg_out_kernel<<<(NE + 255) / 256, 256, 0, stream>>>(src, deg_out);
  rs_out_kernel<<<nblk, 256, 0, stream>>>(deg_out, rs_out);

  // CSR build (two-level counting sort)
  csr_p1<<<PB, 256, 0, stream>>>(dst, counts);
  csr_scan<<<1, 256, 0, stream>>>(counts);
  csr_p2<<<PB, 256, 0, stream>>>(src, dst, counts, recs);
  csr_p3<<<KB, 256, 0, stream>>>(recs, counts, csr_src, cursor_end, deg_in, rs_in);

  const int gablocks = (NN + 7) / 8;   // 12500
  const int gmblocks = (NN + 63) / 64; // 1563

  // Layer 1
  gather_agg_bf16<<<gablocks, 256, 0, stream>>>(buf1, csr_src, cursor_end, deg_in, rs_out, buf2);
  gemm_mfma<<<gmblocks, 256, 0, stream>>>(buf2, Wt1, b1, rs_in, buf3);

  // Layer 2
  gather_agg_bf16<<<gablocks, 256, 0, stream>>>(buf3, csr_src, cursor_end, deg_in, rs_out, buf1);
  gemm_mfma<<<gmblocks, 256, 0, stream>>>(buf1, Wt2, b2, rs_in, buf2);

  // Pool + head
  pool_kernel<<<nblk, 128, 0, stream>>>(buf2, gid, pooled, cnt);
  final_kernel<<<1, 128, 0, stream>>>(pooled, cnt, pa, lW, lb, out);
}

// Round 5
// 429.549 us; speedup vs baseline: 1.6300x; 1.2018x over previous
//
#include <hip/hip_runtime.h>
#include <hip/hip_bf16.h>

#define NN 100000
#define NE 1600000
#define DD 128
#define NG 8

#define KB 98        // dst buckets (dst >> 10)
#define BSH 10
#define PB 128       // phase-1/2 blocks
#define CHUNK 12500  // NE / PB exactly
#define SCAN_N (KB * PB)  // 12544

typedef unsigned short u16;
typedef __attribute__((ext_vector_type(8))) short short8;
typedef __attribute__((ext_vector_type(8))) unsigned short ushort8;
typedef __attribute__((ext_vector_type(4))) float f32x4;

static __device__ __forceinline__ float bf2f(u16 u) {
  return __uint_as_float(((unsigned)u) << 16);
}
static __device__ __forceinline__ u16 f2bf(float f) {
  unsigned u = __float_as_uint(f);
  u += 0x7fffu + ((u >> 16) & 1);
  return (u16)(u >> 16);
}

__global__ void fill_zero(float* __restrict__ p, int n4) {
  int i = blockIdx.x * blockDim.x + threadIdx.x;
  if (i < n4) ((float4*)p)[i] = make_float4(0.f, 0.f, 0.f, 0.f);
}

__global__ void fill_zero_i(int* __restrict__ p, int n4) {
  int i = blockIdx.x * blockDim.x + threadIdx.x;
  if (i < n4) ((int4*)p)[i] = make_int4(0, 0, 0, 0);
}

// out[n][d] = bf16(x[n][d] * rs_out[n]); one thread = 8 elems
__global__ void conv_xscale(const float* __restrict__ in, const float* __restrict__ rs_out,
                            u16* __restrict__ out, int n8) {
  int i = blockIdx.x * blockDim.x + threadIdx.x;
  if (i >= n8) return;
  float w = rs_out[i >> 4];   // 16 chunks of 8 per 128-row
  const float4* p = (const float4*)(in + (size_t)i * 8);
  float4 a = p[0], b = p[1];
  uint4 v;
  v.x = (unsigned)f2bf(a.x * w) | ((unsigned)f2bf(a.y * w) << 16);
  v.y = (unsigned)f2bf(a.z * w) | ((unsigned)f2bf(a.w * w) << 16);
  v.z = (unsigned)f2bf(b.x * w) | ((unsigned)f2bf(b.y * w) << 16);
  v.w = (unsigned)f2bf(b.z * w) | ((unsigned)f2bf(b.w * w) << 16);
  *(uint4*)(out + (size_t)i * 8) = v;
}

__global__ void conv_w_transpose(const float* __restrict__ W, u16* __restrict__ Wt) {
  int idx = blockIdx.x * blockDim.x + threadIdx.x;
  if (idx >= DD * DD) return;
  int n = idx >> 7, k = idx & 127;
  Wt[idx] = f2bf(W[k * DD + n]);
}

__global__ void deg_out_kernel(const int* __restrict__ src, int* __restrict__ dout) {
  int e = blockIdx.x * blockDim.x + threadIdx.x;
  if (e < NE) atomicAdd(&dout[src[e]], 1);
}

__global__ void rs_out_kernel(const int* __restrict__ dout, float* __restrict__ rs_out) {
  int i = blockIdx.x * blockDim.x + threadIdx.x;
  if (i < NN) rs_out[i] = rsqrtf(fmaxf((float)dout[i], 1.f));
}

// ---- CSR build: two-level counting sort ----
__global__ __launch_bounds__(256) void csr_p1(const int* __restrict__ dst,
                                              int* __restrict__ counts) {
  __shared__ int hist[KB];
  int t = threadIdx.x, blk = blockIdx.x;
  for (int i = t; i < KB; i += 256) hist[i] = 0;
  __syncthreads();
  int e0 = blk * CHUNK;
  for (int i = t; i < CHUNK; i += 256) atomicAdd(&hist[dst[e0 + i] >> BSH], 1);
  __syncthreads();
  for (int i = t; i < KB; i += 256) counts[i * PB + blk] = hist[i];
}

__global__ __launch_bounds__(256) void csr_scan(int* __restrict__ counts) {
  __shared__ int data[SCAN_N];   // 50 KB
  __shared__ int part[256];
  int t = threadIdx.x;
  const int per = (SCAN_N + 255) / 256;  // 49
  for (int i = t; i < SCAN_N; i += 256) data[i] = counts[i];
  __syncthreads();
  int base = t * per;
  int s = 0;
  for (int i = 0; i < per; ++i) {
    int idx = base + i;
    if (idx < SCAN_N) s += data[idx];
  }
  part[t] = s;
  __syncthreads();
  for (int off = 1; off < 256; off <<= 1) {
    int v = (t >= off) ? part[t - off] : 0;
    __syncthreads();
    part[t] += v;
    __syncthreads();
  }
  int run = (t == 0) ? 0 : part[t - 1];
  for (int i = 0; i < per; ++i) {
    int idx = base + i;
    if (idx < SCAN_N) {
      int v = data[idx];
      data[idx] = run;
      run += v;
    }
  }
  __syncthreads();
  for (int i = t; i < SCAN_N; i += 256) counts[i] = data[i];
}

__global__ __launch_bounds__(256) void csr_p2(const int* __restrict__ src,
                                              const int* __restrict__ dst,
                                              const int* __restrict__ scanned,
                                              unsigned* __restrict__ recs) {
  __shared__ int cur[KB];
  int t = threadIdx.x, blk = blockIdx.x;
  for (int i = t; i < KB; i += 256) cur[i] = scanned[i * PB + blk];
  __syncthreads();
  int e0 = blk * CHUNK;
  for (int i = t; i < CHUNK; i += 256) {
    int s = src[e0 + i];
    int d = dst[e0 + i];
    int k = d >> BSH;
    int pos = atomicAdd(&cur[k], 1);
    recs[pos] = (unsigned)s | ((unsigned)(d & ((1 << BSH) - 1)) << 17);
  }
}

// One block per bucket: per-node degree, offsets, deg_in/rs_in/cursor_end, csr scatter.
__global__ __launch_bounds__(256) void csr_p3(const unsigned* __restrict__ recs,
                                              const int* __restrict__ scanned,
                                              int* __restrict__ csr_src,
                                              int* __restrict__ cursor_end,
                                              int* __restrict__ deg_in,
                                              float* __restrict__ rs_in) {
  __shared__ int hist[1 << BSH];  // 1024
  __shared__ int part[256];
  int k = blockIdx.x, t = threadIdx.x;
  int rbeg = scanned[k * PB];
  int rend = (k < KB - 1) ? scanned[(k + 1) * PB] : NE;
  int nbase = k << BSH;
  for (int i = t; i < (1 << BSH); i += 256) hist[i] = 0;
  __syncthreads();
  for (int i = rbeg + t; i < rend; i += 256) atomicAdd(&hist[recs[i] >> 17], 1);
  __syncthreads();
  int h[4];
#pragma unroll
  for (int j = 0; j < 4; ++j) h[j] = hist[t * 4 + j];
  part[t] = h[0] + h[1] + h[2] + h[3];
  __syncthreads();
  for (int off = 1; off < 256; off <<= 1) {
    int v = (t >= off) ? part[t - off] : 0;
    __syncthreads();
    part[t] += v;
    __syncthreads();
  }
  int run = rbeg + ((t == 0) ? 0 : part[t - 1]);
#pragma unroll
  for (int j = 0; j < 4; ++j) {
    int n = nbase + t * 4 + j;
    if (n < NN) {
      cursor_end[n] = run + h[j];
      deg_in[n] = h[j];
      rs_in[n] = rsqrtf(fmaxf((float)h[j], 1.f));
    }
    hist[t * 4 + j] = run;   // running write cursor (start)
    run += h[j];
  }
  __syncthreads();
  for (int i = rbeg + t; i < rend; i += 256) {
    unsigned r = recs[i];
    int pos = atomicAdd(&hist[r >> 17], 1);
    csr_src[pos] = (int)(r & 0x1FFFF);
  }
}

// One 16-lane group per dst node; lane q covers bf16 elems 8q..8q+7 (16B).
// H rows are PRE-SCALED by rs_out -> inner loop is idx -> row -> add.
__global__ __launch_bounds__(256) void gather_agg_bf16(
    const u16* __restrict__ H, const int* __restrict__ csr_src,
    const int* __restrict__ cursor_end, const int* __restrict__ deg_in,
    u16* __restrict__ agg) {
  int node = blockIdx.x * 16 + (threadIdx.x >> 4);
  if (node >= NN) return;
  int q = threadIdx.x & 15;
  int end = cursor_end[node];
  int j = end - deg_in[node];
  const ushort8* Hv = (const ushort8*)H;   // row = 16 ushort8
  float a0 = 0.f, a1 = 0.f, a2 = 0.f, a3 = 0.f, a4 = 0.f, a5 = 0.f, a6 = 0.f, a7 = 0.f;
#define ACC8(v) { a0 += bf2f((v)[0]); a1 += bf2f((v)[1]); a2 += bf2f((v)[2]); a3 += bf2f((v)[3]); \
                  a4 += bf2f((v)[4]); a5 += bf2f((v)[5]); a6 += bf2f((v)[6]); a7 += bf2f((v)[7]); }
  for (; j + 4 <= end; j += 4) {
    int s0 = csr_src[j + 0];
    int s1 = csr_src[j + 1];
    int s2 = csr_src[j + 2];
    int s3 = csr_src[j + 3];
    ushort8 v0 = Hv[(size_t)s0 * 16 + q];
    ushort8 v1 = Hv[(size_t)s1 * 16 + q];
    ushort8 v2 = Hv[(size_t)s2 * 16 + q];
    ushort8 v3 = Hv[(size_t)s3 * 16 + q];
    ACC8(v0) ACC8(v1) ACC8(v2) ACC8(v3)
  }
  for (; j < end; ++j) {
    int s = csr_src[j];
    ushort8 v = Hv[(size_t)s * 16 + q];
    ACC8(v)
  }
#undef ACC8
  uint4 o;
  o.x = (unsigned)f2bf(a0) | ((unsigned)f2bf(a1) << 16);
  o.y = (unsigned)f2bf(a2) | ((unsigned)f2bf(a3) << 16);
  o.z = (unsigned)f2bf(a4) | ((unsigned)f2bf(a5) << 16);
  o.w = (unsigned)f2bf(a6) | ((unsigned)f2bf(a7) << 16);
  *(uint4*)(agg + (size_t)node * DD + q * 8) = o;
}

// C[r][c] = relu((A@W)[r][c] * rs[r] + bias[c]) * (post ? post[r] : 1), bf16 out.
__global__ __launch_bounds__(256) void gemm_mfma(
    const u16* __restrict__ Ab, const u16* __restrict__ Wt,
    const float* __restrict__ bias, const float* __restrict__ rs,
    const float* __restrict__ post, u16* __restrict__ Cb) {
  int wid = threadIdx.x >> 6;
  int lane = threadIdx.x & 63;
  int row0 = blockIdx.x * 64 + wid * 16;
  int l15 = lane & 15;
  int kg = lane >> 4;
  int arow = row0 + l15;
  bool rowok = arow < NN;
  const u16* aptr = Ab + (size_t)arow * DD + kg * 8;
  const u16* bbase = Wt + (size_t)l15 * DD + kg * 8;
  f32x4 acc[8];
#pragma unroll
  for (int n = 0; n < 8; ++n) acc[n] = (f32x4){0.f, 0.f, 0.f, 0.f};
#pragma unroll
  for (int kt = 0; kt < 4; ++kt) {
    short8 a = (short8){0, 0, 0, 0, 0, 0, 0, 0};
    if (rowok) a = *(const short8*)(aptr + kt * 32);
#pragma unroll
    for (int n = 0; n < 8; ++n) {
      short8 b = *(const short8*)(bbase + (size_t)n * 16 * DD + kt * 32);
      acc[n] = __builtin_amdgcn_mfma_f32_16x16x32_bf16(a, b, acc[n], 0, 0, 0);
    }
  }
  int crow0 = row0 + kg * 4;
#pragma unroll
  for (int j = 0; j < 4; ++j) {
    int r = crow0 + j;
    if (r < NN) {
      float s = rs[r];
      float ps = post ? post[r] : 1.f;
#pragma unroll
      for (int n = 0; n < 8; ++n) {
        float v = fmaxf(acc[n][j] * s + bias[n * 16 + l15], 0.f) * ps;
        Cb[(size_t)r * DD + n * 16 + l15] = f2bf(v);
      }
    }
  }
}

__global__ __launch_bounds__(128) void pool_kernel(const u16* __restrict__ H,
                                                   const int* __restrict__ gid,
                                                   float* __restrict__ pooled,
                                                   float* __restrict__ cnt) {
  __shared__ int gs[256];
  int t = threadIdx.x;
  int n0 = blockIdx.x * 256;
  int nn = NN - n0;
  if (nn > 256) nn = 256;
  if (nn <= 0) return;
  for (int i = t; i < nn; i += 128) gs[i] = gid[n0 + i];
  __syncthreads();
  int curg = gs[0];
  float acc = 0.f;
  float c = 0.f;
  for (int i = 0; i < nn; ++i) {
    int g = gs[i];
    if (g != curg) {
      atomicAdd(&pooled[curg * DD + t], acc);
      if (t == 0) atomicAdd(&cnt[curg], c);
      acc = 0.f;
      c = 0.f;
      curg = g;
    }
    acc += bf2f(H[(size_t)(n0 + i) * DD + t]);
    c += 1.f;
  }
  atomicAdd(&pooled[curg * DD + t], acc);
  if (t == 0) atomicAdd(&cnt[curg], c);
}

__global__ __launch_bounds__(128) void final_kernel(const float* __restrict__ pooled,
                                                    const float* __restrict__ cnt,
                                                    const float* __restrict__ prelu_a,
                                                    const float* __restrict__ linW,
                                                    const float* __restrict__ linb,
                                                    float* __restrict__ out) {
  int t = threadIdx.x;  // 128
  __shared__ float red[2];
  float w = linW[t];
  float alpha = prelu_a[0];
  float lb = linb[0];
  for (int g = 0; g < NG; ++g) {
    float v = pooled[g * DD + t] / fmaxf(cnt[g], 1.f);
    v = v > 0.f ? v : alpha * v;
    float p = v * w;
#pragma unroll
    for (int off = 32; off >= 1; off >>= 1) p += __shfl_down(p, off, 64);
    if ((t & 63) == 0) red[t >> 6] = p;
    __syncthreads();
    if (t == 0) {
      float s = red[0] + red[1] + lb;
      out[g] = 1.f / (1.f + expf(-s));
    }
    __syncthreads();
  }
}

extern "C" void kernel_launch(void* const* d_in, const int* in_sizes, int n_in,
                              void* d_out, int out_size, void* d_ws, size_t ws_size,
                              hipStream_t stream) {
  const float* x   = (const float*)d_in[0];
  const int*   src = (const int*)d_in[1];
  const int*   dst = (const int*)d_in[2];
  const int*   gid = (const int*)d_in[3];
  const float* W1  = (const float*)d_in[4];
  const float* b1  = (const float*)d_in[5];
  const float* W2  = (const float*)d_in[6];
  const float* b2  = (const float*)d_in[7];
  const float* pa  = (const float*)d_in[8];
  const float* lW  = (const float*)d_in[9];
  const float* lb  = (const float*)d_in[10];
  float* out = (float*)d_out;

  char* ws = (char*)d_ws;
  size_t o = 0;
  auto alloc = [&](size_t bytes) {
    size_t r = o;
    o += (bytes + 255) & ~(size_t)255;
    return r;
  };
  int*   deg_out = (int*)(ws + alloc((size_t)NN * 4));
  int*   deg_in  = (int*)(ws + alloc((size_t)NN * 4));
  float* rs_out  = (float*)(ws + alloc((size_t)NN * 4));
  float* rs_in   = (float*)(ws + alloc((size_t)NN * 4));
  int*   counts  = (int*)(ws + alloc((size_t)SCAN_N * 4));
  int*   cursor_end = (int*)(ws + alloc((size_t)NN * 4));
  unsigned* recs = (unsigned*)(ws + alloc((size_t)NE * 4));
  int*   csr_src = (int*)(ws + alloc((size_t)NE * 4));
  u16*   Wt1     = (u16*)(ws + alloc((size_t)DD * DD * 2));
  u16*   Wt2     = (u16*)(ws + alloc((size_t)DD * DD * 2));
  u16*   buf1    = (u16*)(ws + alloc((size_t)NN * DD * 2));
  u16*   buf2    = (u16*)(ws + alloc((size_t)NN * DD * 2));
  u16*   buf3    = (u16*)(ws + alloc((size_t)NN * DD * 2));
  float* pooled  = (float*)(ws + alloc((size_t)(NG * DD + NG) * 4));
  float* cnt     = pooled + NG * DD;

  const int nblk = (NN + 255) / 256;  // 391

  fill_zero_i<<<(NN / 4 + 255) / 256, 256, 0, stream>>>(deg_out, NN / 4);
  fill_zero<<<2, 256, 0, stream>>>(pooled, (NG * DD + NG + 3) / 4);

  deg_out_kernel<<<(NE + 255) / 256, 256, 0, stream>>>(src, deg_out);
  rs_out_kernel<<<nblk, 256, 0, stream>>>(deg_out, rs_out);

  // x -> bf16, pre-scaled by rs_out (needs rs_out ready)
  conv_xscale<<<(NN * DD / 8 + 255) / 256, 256, 0, stream>>>(x, rs_out, buf1, NN * DD / 8);
  conv_w_transpose<<<64, 256, 0, stream>>>(W1, Wt1);
  conv_w_transpose<<<64, 256, 0, stream>>>(W2, Wt2);

  // CSR build (two-level counting sort)
  csr_p1<<<PB, 256, 0, stream>>>(dst, counts);
  csr_scan<<<1, 256, 0, stream>>>(counts);
  csr_p2<<<PB, 256, 0, stream>>>(src, dst, counts, recs);
  csr_p3<<<KB, 256, 0, stream>>>(recs, counts, csr_src, cursor_end, deg_in, rs_in);

  const int gablocks = (NN + 15) / 16;  // 6250
  const int gmblocks = (NN + 63) / 64;  // 1563

  // Layer 1: gather pre-scaled x, GEMM epilogue emits h1 * rs_out (feeds gather 2)
  gather_agg_bf16<<<gablocks, 256, 0, stream>>>(buf1, csr_src, cursor_end, deg_in, buf2);
  gemm_mfma<<<gmblocks, 256, 0, stream>>>(buf2, Wt1, b1, rs_in, rs_out, buf3);

  // Layer 2: plain h2 out (feeds pool)
  gather_agg_bf16<<<gablocks, 256, 0, stream>>>(buf3, csr_src, cursor_end, deg_in, buf1);
  gemm_mfma<<<gmblocks, 256, 0, stream>>>(buf1, Wt2, b2, rs_in, nullptr, buf2);

  // Pool + head
  pool_kernel<<<nblk, 128, 0, stream>>>(buf2, gid, pooled, cnt);
  final_kernel<<<1, 128, 0, stream>>>(pooled, cnt, pa, lW, lb, out);
}

// Round 6
// 381.608 us; speedup vs baseline: 1.8348x; 1.1256x over previous
//
#include <hip/hip_runtime.h>
#include <hip/hip_bf16.h>

#define NN 100000
#define NE 1600000
#define DD 128
#define NG 8

#define KB 98        // dst buckets (dst >> 10)
#define BSH 10
#define PB 128       // phase-1/2 blocks
#define CHUNK 12500  // NE / PB exactly
#define SCAN_N (KB * PB)  // 12544

typedef unsigned short u16;
typedef __attribute__((ext_vector_type(8))) short short8;
typedef __attribute__((ext_vector_type(8))) unsigned short ushort8;
typedef __attribute__((ext_vector_type(4))) float f32x4;

static __device__ __forceinline__ float bf2f(u16 u) {
  return __uint_as_float(((unsigned)u) << 16);
}
static __device__ __forceinline__ u16 f2bf(float f) {
  unsigned u = __float_as_uint(f);
  u += 0x7fffu + ((u >> 16) & 1);
  return (u16)(u >> 16);
}

__global__ void fill_zero(float* __restrict__ p, int n4) {
  int i = blockIdx.x * blockDim.x + threadIdx.x;
  if (i < n4) ((float4*)p)[i] = make_float4(0.f, 0.f, 0.f, 0.f);
}

__global__ void fill_zero_i(int* __restrict__ p, int n4) {
  int i = blockIdx.x * blockDim.x + threadIdx.x;
  if (i < n4) ((int4*)p)[i] = make_int4(0, 0, 0, 0);
}

// out[n][d] = bf16(x[n][d] * rs_out[n]); one thread = 8 elems
__global__ void conv_xscale(const float* __restrict__ in, const float* __restrict__ rs_out,
                            u16* __restrict__ out, int n8) {
  int i = blockIdx.x * blockDim.x + threadIdx.x;
  if (i >= n8) return;
  float w = rs_out[i >> 4];   // 16 chunks of 8 per 128-row
  const float4* p = (const float4*)(in + (size_t)i * 8);
  float4 a = p[0], b = p[1];
  uint4 v;
  v.x = (unsigned)f2bf(a.x * w) | ((unsigned)f2bf(a.y * w) << 16);
  v.y = (unsigned)f2bf(a.z * w) | ((unsigned)f2bf(a.w * w) << 16);
  v.z = (unsigned)f2bf(b.x * w) | ((unsigned)f2bf(b.y * w) << 16);
  v.w = (unsigned)f2bf(b.z * w) | ((unsigned)f2bf(b.w * w) << 16);
  *(uint4*)(out + (size_t)i * 8) = v;
}

__global__ void conv_w_transpose(const float* __restrict__ W, u16* __restrict__ Wt) {
  int idx = blockIdx.x * blockDim.x + threadIdx.x;
  if (idx >= DD * DD) return;
  int n = idx >> 7, k = idx & 127;
  Wt[idx] = f2bf(W[k * DD + n]);
}

__global__ void deg_out_kernel(const int* __restrict__ src, int* __restrict__ dout) {
  int e = blockIdx.x * blockDim.x + threadIdx.x;
  if (e < NE) atomicAdd(&dout[src[e]], 1);
}

__global__ void rs_out_kernel(const int* __restrict__ dout, float* __restrict__ rs_out) {
  int i = blockIdx.x * blockDim.x + threadIdx.x;
  if (i < NN) rs_out[i] = rsqrtf(fmaxf((float)dout[i], 1.f));
}

__global__ __launch_bounds__(256) void histo_gid(const int* __restrict__ gid,
                                                 int* __restrict__ cnt) {
  __shared__ int h[NG];
  int t = threadIdx.x;
  if (t < NG) h[t] = 0;
  __syncthreads();
  for (int i = blockIdx.x * 256 + t; i < NN; i += gridDim.x * 256)
    atomicAdd(&h[gid[i]], 1);
  __syncthreads();
  if (t < NG && h[t]) atomicAdd(&cnt[t], h[t]);
}

// ---- CSR build: two-level counting sort ----
__global__ __launch_bounds__(256) void csr_p1(const int* __restrict__ dst,
                                              int* __restrict__ counts) {
  __shared__ int hist[KB];
  int t = threadIdx.x, blk = blockIdx.x;
  for (int i = t; i < KB; i += 256) hist[i] = 0;
  __syncthreads();
  int e0 = blk * CHUNK;
  for (int i = t; i < CHUNK; i += 256) atomicAdd(&hist[dst[e0 + i] >> BSH], 1);
  __syncthreads();
  for (int i = t; i < KB; i += 256) counts[i * PB + blk] = hist[i];
}

__global__ __launch_bounds__(256) void csr_scan(int* __restrict__ counts) {
  __shared__ int data[SCAN_N];   // 50 KB
  __shared__ int part[256];
  int t = threadIdx.x;
  const int per = (SCAN_N + 255) / 256;  // 49
  for (int i = t; i < SCAN_N; i += 256) data[i] = counts[i];
  __syncthreads();
  int base = t * per;
  int s = 0;
  for (int i = 0; i < per; ++i) {
    int idx = base + i;
    if (idx < SCAN_N) s += data[idx];
  }
  part[t] = s;
  __syncthreads();
  for (int off = 1; off < 256; off <<= 1) {
    int v = (t >= off) ? part[t - off] : 0;
    __syncthreads();
    part[t] += v;
    __syncthreads();
  }
  int run = (t == 0) ? 0 : part[t - 1];
  for (int i = 0; i < per; ++i) {
    int idx = base + i;
    if (idx < SCAN_N) {
      int v = data[idx];
      data[idx] = run;
      run += v;
    }
  }
  __syncthreads();
  for (int i = t; i < SCAN_N; i += 256) counts[i] = data[i];
}

__global__ __launch_bounds__(256) void csr_p2(const int* __restrict__ src,
                                              const int* __restrict__ dst,
                                              const int* __restrict__ scanned,
                                              unsigned* __restrict__ recs) {
  __shared__ int cur[KB];
  int t = threadIdx.x, blk = blockIdx.x;
  for (int i = t; i < KB; i += 256) cur[i] = scanned[i * PB + blk];
  __syncthreads();
  int e0 = blk * CHUNK;
  for (int i = t; i < CHUNK; i += 256) {
    int s = src[e0 + i];
    int d = dst[e0 + i];
    int k = d >> BSH;
    int pos = atomicAdd(&cur[k], 1);
    recs[pos] = (unsigned)s | ((unsigned)(d & ((1 << BSH) - 1)) << 17);
  }
}

// One block per bucket: per-node degree, offsets, deg_in/rs_in/cursor_end, csr scatter.
__global__ __launch_bounds__(256) void csr_p3(const unsigned* __restrict__ recs,
                                              const int* __restrict__ scanned,
                                              int* __restrict__ csr_src,
                                              int* __restrict__ cursor_end,
                                              int* __restrict__ deg_in,
                                              float* __restrict__ rs_in) {
  __shared__ int hist[1 << BSH];  // 1024
  __shared__ int part[256];
  int k = blockIdx.x, t = threadIdx.x;
  int rbeg = scanned[k * PB];
  int rend = (k < KB - 1) ? scanned[(k + 1) * PB] : NE;
  int nbase = k << BSH;
  for (int i = t; i < (1 << BSH); i += 256) hist[i] = 0;
  __syncthreads();
  for (int i = rbeg + t; i < rend; i += 256) atomicAdd(&hist[recs[i] >> 17], 1);
  __syncthreads();
  int h[4];
#pragma unroll
  for (int j = 0; j < 4; ++j) h[j] = hist[t * 4 + j];
  part[t] = h[0] + h[1] + h[2] + h[3];
  __syncthreads();
  for (int off = 1; off < 256; off <<= 1) {
    int v = (t >= off) ? part[t - off] : 0;
    __syncthreads();
    part[t] += v;
    __syncthreads();
  }
  int run = rbeg + ((t == 0) ? 0 : part[t - 1]);
#pragma unroll
  for (int j = 0; j < 4; ++j) {
    int n = nbase + t * 4 + j;
    if (n < NN) {
      cursor_end[n] = run + h[j];
      deg_in[n] = h[j];
      rs_in[n] = rsqrtf(fmaxf((float)h[j], 1.f));
    }
    hist[t * 4 + j] = run;   // running write cursor (start)
    run += h[j];
  }
  __syncthreads();
  for (int i = rbeg + t; i < rend; i += 256) {
    unsigned r = recs[i];
    int pos = atomicAdd(&hist[r >> 17], 1);
    csr_src[pos] = (int)(r & 0x1FFFF);
  }
}

// One 16-lane group per dst node; lane q covers bf16 elems 8q..8q+7 (16B).
// H rows are PRE-SCALED by rs_out -> inner loop is idx -> row -> add.
__global__ __launch_bounds__(256) void gather_agg_bf16(
    const u16* __restrict__ H, const int* __restrict__ csr_src,
    const int* __restrict__ cursor_end, const int* __restrict__ deg_in,
    u16* __restrict__ agg) {
  int node = blockIdx.x * 16 + (threadIdx.x >> 4);
  if (node >= NN) return;
  int q = threadIdx.x & 15;
  int end = cursor_end[node];
  int j = end - deg_in[node];
  const ushort8* Hv = (const ushort8*)H;   // row = 16 ushort8
  float a0 = 0.f, a1 = 0.f, a2 = 0.f, a3 = 0.f, a4 = 0.f, a5 = 0.f, a6 = 0.f, a7 = 0.f;
#define ACC8(v) { a0 += bf2f((v)[0]); a1 += bf2f((v)[1]); a2 += bf2f((v)[2]); a3 += bf2f((v)[3]); \
                  a4 += bf2f((v)[4]); a5 += bf2f((v)[5]); a6 += bf2f((v)[6]); a7 += bf2f((v)[7]); }
  for (; j + 4 <= end; j += 4) {
    int s0 = csr_src[j + 0];
    int s1 = csr_src[j + 1];
    int s2 = csr_src[j + 2];
    int s3 = csr_src[j + 3];
    ushort8 v0 = Hv[(size_t)s0 * 16 + q];
    ushort8 v1 = Hv[(size_t)s1 * 16 + q];
    ushort8 v2 = Hv[(size_t)s2 * 16 + q];
    ushort8 v3 = Hv[(size_t)s3 * 16 + q];
    ACC8(v0) ACC8(v1) ACC8(v2) ACC8(v3)
  }
  for (; j < end; ++j) {
    int s = csr_src[j];
    ushort8 v = Hv[(size_t)s * 16 + q];
    ACC8(v)
  }
#undef ACC8
  uint4 o;
  o.x = (unsigned)f2bf(a0) | ((unsigned)f2bf(a1) << 16);
  o.y = (unsigned)f2bf(a2) | ((unsigned)f2bf(a3) << 16);
  o.z = (unsigned)f2bf(a4) | ((unsigned)f2bf(a5) << 16);
  o.w = (unsigned)f2bf(a6) | ((unsigned)f2bf(a7) << 16);
  *(uint4*)(agg + (size_t)node * DD + q * 8) = o;
}

// C[r][c] = relu((A@W)[r][c] * rs[r] + bias[c]) * post[r], bf16 out to Cb.
__global__ __launch_bounds__(256) void gemm_mfma(
    const u16* __restrict__ Ab, const u16* __restrict__ Wt,
    const float* __restrict__ bias, const float* __restrict__ rs,
    const float* __restrict__ post, u16* __restrict__ Cb) {
  int wid = threadIdx.x >> 6;
  int lane = threadIdx.x & 63;
  int row0 = blockIdx.x * 64 + wid * 16;
  int l15 = lane & 15;
  int kg = lane >> 4;
  int arow = row0 + l15;
  bool rowok = arow < NN;
  const u16* aptr = Ab + (size_t)arow * DD + kg * 8;
  const u16* bbase = Wt + (size_t)l15 * DD + kg * 8;
  f32x4 acc[8];
#pragma unroll
  for (int n = 0; n < 8; ++n) acc[n] = (f32x4){0.f, 0.f, 0.f, 0.f};
#pragma unroll
  for (int kt = 0; kt < 4; ++kt) {
    short8 a = (short8){0, 0, 0, 0, 0, 0, 0, 0};
    if (rowok) a = *(const short8*)(aptr + kt * 32);
#pragma unroll
    for (int n = 0; n < 8; ++n) {
      short8 b = *(const short8*)(bbase + (size_t)n * 16 * DD + kt * 32);
      acc[n] = __builtin_amdgcn_mfma_f32_16x16x32_bf16(a, b, acc[n], 0, 0, 0);
    }
  }
  int crow0 = row0 + kg * 4;
#pragma unroll
  for (int j = 0; j < 4; ++j) {
    int r = crow0 + j;
    if (r < NN) {
      float s = rs[r];
      float ps = post[r];
#pragma unroll
      for (int n = 0; n < 8; ++n) {
        float v = fmaxf(acc[n][j] * s + bias[n * 16 + l15], 0.f) * ps;
        Cb[(size_t)r * DD + n * 16 + l15] = f2bf(v);
      }
    }
  }
}

// Layer-2 GEMM with pooling fused into the epilogue: no Cb output.
__global__ __launch_bounds__(256) void gemm_mfma_pool(
    const u16* __restrict__ Ab, const u16* __restrict__ Wt,
    const float* __restrict__ bias, const float* __restrict__ rs,
    const int* __restrict__ gid, float* __restrict__ pooled) {
  __shared__ float pl[NG * DD];  // 4 KB
  int tid = threadIdx.x;
  for (int i = tid; i < NG * DD; i += 256) pl[i] = 0.f;
  __syncthreads();

  int wid = tid >> 6;
  int lane = tid & 63;
  int row0 = blockIdx.x * 64 + wid * 16;
  int l15 = lane & 15;
  int kg = lane >> 4;
  int arow = row0 + l15;
  bool rowok = arow < NN;
  const u16* aptr = Ab + (size_t)arow * DD + kg * 8;
  const u16* bbase = Wt + (size_t)l15 * DD + kg * 8;
  f32x4 acc[8];
#pragma unroll
  for (int n = 0; n < 8; ++n) acc[n] = (f32x4){0.f, 0.f, 0.f, 0.f};
#pragma unroll
  for (int kt = 0; kt < 4; ++kt) {
    short8 a = (short8){0, 0, 0, 0, 0, 0, 0, 0};
    if (rowok) a = *(const short8*)(aptr + kt * 32);
#pragma unroll
    for (int n = 0; n < 8; ++n) {
      short8 b = *(const short8*)(bbase + (size_t)n * 16 * DD + kt * 32);
      acc[n] = __builtin_amdgcn_mfma_f32_16x16x32_bf16(a, b, acc[n], 0, 0, 0);
    }
  }
  int crow0 = row0 + kg * 4;
  float pacc[8];
#pragma unroll
  for (int n = 0; n < 8; ++n) pacc[n] = 0.f;
  int curg = -1;
#pragma unroll
  for (int j = 0; j < 4; ++j) {
    int r = crow0 + j;
    if (r < NN) {
      int g = gid[r];
      if (g != curg) {
        if (curg >= 0) {
#pragma unroll
          for (int n = 0; n < 8; ++n) {
            atomicAdd(&pl[curg * DD + n * 16 + l15], pacc[n]);
            pacc[n] = 0.f;
          }
        }
        curg = g;
      }
      float s = rs[r];
#pragma unroll
      for (int n = 0; n < 8; ++n)
        pacc[n] += fmaxf(acc[n][j] * s + bias[n * 16 + l15], 0.f);
    }
  }
  if (curg >= 0) {
#pragma unroll
    for (int n = 0; n < 8; ++n)
      atomicAdd(&pl[curg * DD + n * 16 + l15], pacc[n]);
  }
  __syncthreads();
  for (int i = tid; i < NG * DD; i += 256) {
    float v = pl[i];
    if (v != 0.f) atomicAdd(&pooled[i], v);
  }
}

__global__ __launch_bounds__(128) void final_kernel(const float* __restrict__ pooled,
                                                    const int* __restrict__ cnt,
                                                    const float* __restrict__ prelu_a,
                                                    const float* __restrict__ linW,
                                                    const float* __restrict__ linb,
                                                    float* __restrict__ out) {
  int t = threadIdx.x;  // 128
  __shared__ float red[2];
  float w = linW[t];
  float alpha = prelu_a[0];
  float lb = linb[0];
  for (int g = 0; g < NG; ++g) {
    float v = pooled[g * DD + t] / fmaxf((float)cnt[g], 1.f);
    v = v > 0.f ? v : alpha * v;
    float p = v * w;
#pragma unroll
    for (int off = 32; off >= 1; off >>= 1) p += __shfl_down(p, off, 64);
    if ((t & 63) == 0) red[t >> 6] = p;
    __syncthreads();
    if (t == 0) {
      float s = red[0] + red[1] + lb;
      out[g] = 1.f / (1.f + expf(-s));
    }
    __syncthreads();
  }
}

extern "C" void kernel_launch(void* const* d_in, const int* in_sizes, int n_in,
                              void* d_out, int out_size, void* d_ws, size_t ws_size,
                              hipStream_t stream) {
  const float* x   = (const float*)d_in[0];
  const int*   src = (const int*)d_in[1];
  const int*   dst = (const int*)d_in[2];
  const int*   gid = (const int*)d_in[3];
  const float* W1  = (const float*)d_in[4];
  const float* b1  = (const float*)d_in[5];
  const float* W2  = (const float*)d_in[6];
  const float* b2  = (const float*)d_in[7];
  const float* pa  = (const float*)d_in[8];
  const float* lW  = (const float*)d_in[9];
  const float* lb  = (const float*)d_in[10];
  float* out = (float*)d_out;

  char* ws = (char*)d_ws;
  size_t o = 0;
  auto alloc = [&](size_t bytes) {
    size_t r = o;
    o += (bytes + 255) & ~(size_t)255;
    return r;
  };
  int*   deg_out = (int*)(ws + alloc((size_t)NN * 4));
  int*   deg_in  = (int*)(ws + alloc((size_t)NN * 4));
  float* rs_out  = (float*)(ws + alloc((size_t)NN * 4));
  float* rs_in   = (float*)(ws + alloc((size_t)NN * 4));
  int*   counts  = (int*)(ws + alloc((size_t)SCAN_N * 4));
  int*   cursor_end = (int*)(ws + alloc((size_t)NN * 4));
  unsigned* recs = (unsigned*)(ws + alloc((size_t)NE * 4));
  int*   csr_src = (int*)(ws + alloc((size_t)NE * 4));
  u16*   Wt1     = (u16*)(ws + alloc((size_t)DD * DD * 2));
  u16*   Wt2     = (u16*)(ws + alloc((size_t)DD * DD * 2));
  u16*   buf1    = (u16*)(ws + alloc((size_t)NN * DD * 2));
  u16*   buf2    = (u16*)(ws + alloc((size_t)NN * DD * 2));
  u16*   buf3    = (u16*)(ws + alloc((size_t)NN * DD * 2));
  float* pooled  = (float*)(ws + alloc((size_t)(NG * DD + NG) * 4));
  int*   cnt     = (int*)(pooled + NG * DD);

  const int nblk = (NN + 255) / 256;  // 391

  fill_zero_i<<<(NN / 4 + 255) / 256, 256, 0, stream>>>(deg_out, NN / 4);
  fill_zero<<<2, 256, 0, stream>>>(pooled, (NG * DD + NG + 3) / 4);

  deg_out_kernel<<<(NE + 255) / 256, 256, 0, stream>>>(src, deg_out);
  rs_out_kernel<<<nblk, 256, 0, stream>>>(deg_out, rs_out);
  histo_gid<<<98, 256, 0, stream>>>(gid, cnt);

  // x -> bf16, pre-scaled by rs_out (needs rs_out ready)
  conv_xscale<<<(NN * DD / 8 + 255) / 256, 256, 0, stream>>>(x, rs_out, buf1, NN * DD / 8);
  conv_w_transpose<<<64, 256, 0, stream>>>(W1, Wt1);
  conv_w_transpose<<<64, 256, 0, stream>>>(W2, Wt2);

  // CSR build (two-level counting sort)
  csr_p1<<<PB, 256, 0, stream>>>(dst, counts);
  csr_scan<<<1, 256, 0, stream>>>(counts);
  csr_p2<<<PB, 256, 0, stream>>>(src, dst, counts, recs);
  csr_p3<<<KB, 256, 0, stream>>>(recs, counts, csr_src, cursor_end, deg_in, rs_in);

  const int gablocks = (NN + 15) / 16;  // 6250
  const int gmblocks = (NN + 63) / 64;  // 1563

  // Layer 1: gather pre-scaled x; GEMM epilogue emits h1 * rs_out (feeds gather 2)
  gather_agg_bf16<<<gablocks, 256, 0, stream>>>(buf1, csr_src, cursor_end, deg_in, buf2);
  gemm_mfma<<<gmblocks, 256, 0, stream>>>(buf2, Wt1, b1, rs_in, rs_out, buf3);

  // Layer 2: gather, then GEMM with fused pooling (no feature output)
  gather_agg_bf16<<<gablocks, 256, 0, stream>>>(buf3, csr_src, cursor_end, deg_in, buf1);
  gemm_mfma_pool<<<gmblocks, 256, 0, stream>>>(buf1, Wt2, b2, rs_in, gid, pooled);

  // Head
  final_kernel<<<1, 128, 0, stream>>>(pooled, cnt, pa, lW, lb, out);
}

// Round 7
// 349.077 us; speedup vs baseline: 2.0058x; 1.0932x over previous
//
#include <hip/hip_runtime.h>
#include <hip/hip_bf16.h>

#define NN 100000
#define NE 1600000
#define DD 128
#define NG 8

#define KB 98        // node buckets (id >> 10)
#define BSH 10
#define PB 128       // phase-1/2 blocks
#define CHUNK 12500  // NE / PB exactly
#define SCAN_N (KB * PB)  // 12544

typedef unsigned short u16;
typedef __attribute__((ext_vector_type(8))) short short8;
typedef __attribute__((ext_vector_type(8))) unsigned short ushort8;
typedef __attribute__((ext_vector_type(4))) float f32x4;

static __device__ __forceinline__ float bf2f(u16 u) {
  return __uint_as_float(((unsigned)u) << 16);
}
static __device__ __forceinline__ u16 f2bf(float f) {
  unsigned u = __float_as_uint(f);
  u += 0x7fffu + ((u >> 16) & 1);
  return (u16)(u >> 16);
}

__global__ void fill_zero(float* __restrict__ p, int n4) {
  int i = blockIdx.x * blockDim.x + threadIdx.x;
  if (i < n4) ((float4*)p)[i] = make_float4(0.f, 0.f, 0.f, 0.f);
}

// out[n][d] = bf16(x[n][d] * rs_out[n]); one thread = 8 elems
__global__ void conv_xscale(const float* __restrict__ in, const float* __restrict__ rs_out,
                            u16* __restrict__ out, int n8) {
  int i = blockIdx.x * blockDim.x + threadIdx.x;
  if (i >= n8) return;
  float w = rs_out[i >> 4];
  const float4* p = (const float4*)(in + (size_t)i * 8);
  float4 a = p[0], b = p[1];
  uint4 v;
  v.x = (unsigned)f2bf(a.x * w) | ((unsigned)f2bf(a.y * w) << 16);
  v.y = (unsigned)f2bf(a.z * w) | ((unsigned)f2bf(a.w * w) << 16);
  v.z = (unsigned)f2bf(b.x * w) | ((unsigned)f2bf(b.y * w) << 16);
  v.w = (unsigned)f2bf(b.z * w) | ((unsigned)f2bf(b.w * w) << 16);
  *(uint4*)(out + (size_t)i * 8) = v;
}

__global__ void conv_w_transpose(const float* __restrict__ W, u16* __restrict__ Wt) {
  int idx = blockIdx.x * blockDim.x + threadIdx.x;
  if (idx >= DD * DD) return;
  int n = idx >> 7, k = idx & 127;
  Wt[idx] = f2bf(W[k * DD + n]);
}

__global__ __launch_bounds__(256) void histo_gid(const int* __restrict__ gid,
                                                 int* __restrict__ cnt) {
  __shared__ int h[NG];
  int t = threadIdx.x;
  if (t < NG) h[t] = 0;
  __syncthreads();
  for (int i = blockIdx.x * 256 + t; i < NN; i += gridDim.x * 256)
    atomicAdd(&h[gid[i]], 1);
  __syncthreads();
  if (t < NG && h[t]) atomicAdd(&cnt[t], h[t]);
}

// ---- combined bucket histograms for src and dst ----
__global__ __launch_bounds__(256) void p1_both(const int* __restrict__ src,
                                               const int* __restrict__ dst,
                                               int* __restrict__ countsS,
                                               int* __restrict__ countsD) {
  __shared__ int hs[KB], hd[KB];
  int t = threadIdx.x, blk = blockIdx.x;
  for (int i = t; i < KB; i += 256) { hs[i] = 0; hd[i] = 0; }
  __syncthreads();
  int e0 = blk * CHUNK;
  for (int i = t; i < CHUNK; i += 256) {
    atomicAdd(&hs[src[e0 + i] >> BSH], 1);
    atomicAdd(&hd[dst[e0 + i] >> BSH], 1);
  }
  __syncthreads();
  for (int i = t; i < KB; i += 256) {
    countsS[i * PB + blk] = hs[i];
    countsD[i * PB + blk] = hd[i];
  }
}

// grid=2: block 0 scans countsD, block 1 scans countsS (exclusive, in place)
__global__ __launch_bounds__(256) void scan2(int* __restrict__ countsD,
                                             int* __restrict__ countsS) {
  __shared__ int data[SCAN_N];   // 50 KB
  __shared__ int part[256];
  int* counts = (blockIdx.x == 0) ? countsD : countsS;
  int t = threadIdx.x;
  const int per = (SCAN_N + 255) / 256;  // 49
  for (int i = t; i < SCAN_N; i += 256) data[i] = counts[i];
  __syncthreads();
  int base = t * per;
  int s = 0;
  for (int i = 0; i < per; ++i) {
    int idx = base + i;
    if (idx < SCAN_N) s += data[idx];
  }
  part[t] = s;
  __syncthreads();
  for (int off = 1; off < 256; off <<= 1) {
    int v = (t >= off) ? part[t - off] : 0;
    __syncthreads();
    part[t] += v;
    __syncthreads();
  }
  int run = (t == 0) ? 0 : part[t - 1];
  for (int i = 0; i < per; ++i) {
    int idx = base + i;
    if (idx < SCAN_N) {
      int v = data[idx];
      data[idx] = run;
      run += v;
    }
  }
  __syncthreads();
  for (int i = t; i < SCAN_N; i += 256) counts[i] = data[i];
}

// combined scatter: recsD (u32, CSR records) + recsS (u16, src low bits)
__global__ __launch_bounds__(256) void p2_both(const int* __restrict__ src,
                                               const int* __restrict__ dst,
                                               const int* __restrict__ scS,
                                               const int* __restrict__ scD,
                                               u16* __restrict__ recsS,
                                               unsigned* __restrict__ recsD) {
  __shared__ int curS[KB], curD[KB];
  int t = threadIdx.x, blk = blockIdx.x;
  for (int i = t; i < KB; i += 256) {
    curS[i] = scS[i * PB + blk];
    curD[i] = scD[i * PB + blk];
  }
  __syncthreads();
  int e0 = blk * CHUNK;
  for (int i = t; i < CHUNK; i += 256) {
    int s = src[e0 + i];
    int d = dst[e0 + i];
    int ps = atomicAdd(&curS[s >> BSH], 1);
    recsS[ps] = (u16)(s & ((1 << BSH) - 1));
    int pd = atomicAdd(&curD[d >> BSH], 1);
    recsD[pd] = (unsigned)s | ((unsigned)(d & ((1 << BSH) - 1)) << 17);
  }
}

// per src-bucket histogram -> rs_out (no deg_out array)
__global__ __launch_bounds__(256) void src_p3(const u16* __restrict__ recsS,
                                              const int* __restrict__ scS,
                                              float* __restrict__ rs_out) {
  __shared__ int hist[1 << BSH];
  int k = blockIdx.x, t = threadIdx.x;
  int rbeg = scS[k * PB];
  int rend = (k < KB - 1) ? scS[(k + 1) * PB] : NE;
  for (int i = t; i < (1 << BSH); i += 256) hist[i] = 0;
  __syncthreads();
  for (int i = rbeg + t; i < rend; i += 256) atomicAdd(&hist[recsS[i]], 1);
  __syncthreads();
  int nbase = k << BSH;
  for (int i = t; i < (1 << BSH); i += 256) {
    int n = nbase + i;
    if (n < NN) rs_out[n] = rsqrtf(fmaxf((float)hist[i], 1.f));
  }
}

// One block per dst bucket: deg_in/rs_in/cursor_end + ordered csr scatter.
__global__ __launch_bounds__(256) void csr_p3(const unsigned* __restrict__ recs,
                                              const int* __restrict__ scanned,
                                              int* __restrict__ csr_src,
                                              int* __restrict__ cursor_end,
                                              int* __restrict__ deg_in,
                                              float* __restrict__ rs_in) {
  __shared__ int hist[1 << BSH];  // 1024
  __shared__ int part[256];
  int k = blockIdx.x, t = threadIdx.x;
  int rbeg = scanned[k * PB];
  int rend = (k < KB - 1) ? scanned[(k + 1) * PB] : NE;
  int nbase = k << BSH;
  for (int i = t; i < (1 << BSH); i += 256) hist[i] = 0;
  __syncthreads();
  for (int i = rbeg + t; i < rend; i += 256) atomicAdd(&hist[recs[i] >> 17], 1);
  __syncthreads();
  int h[4];
#pragma unroll
  for (int j = 0; j < 4; ++j) h[j] = hist[t * 4 + j];
  part[t] = h[0] + h[1] + h[2] + h[3];
  __syncthreads();
  for (int off = 1; off < 256; off <<= 1) {
    int v = (t >= off) ? part[t - off] : 0;
    __syncthreads();
    part[t] += v;
    __syncthreads();
  }
  int run = rbeg + ((t == 0) ? 0 : part[t - 1]);
#pragma unroll
  for (int j = 0; j < 4; ++j) {
    int n = nbase + t * 4 + j;
    if (n < NN) {
      cursor_end[n] = run + h[j];
      deg_in[n] = h[j];
      rs_in[n] = rsqrtf(fmaxf((float)h[j], 1.f));
    }
    hist[t * 4 + j] = run;   // running write cursor (start)
    run += h[j];
  }
  __syncthreads();
  for (int i = rbeg + t; i < rend; i += 256) {
    unsigned r = recs[i];
    int pos = atomicAdd(&hist[r >> 17], 1);
    csr_src[pos] = (int)(r & 0x1FFFF);
  }
}

// One 16-lane group per dst node; lane q covers bf16 elems 8q..8q+7 (16B).
__global__ __launch_bounds__(256) void gather_agg_bf16(
    const u16* __restrict__ H, const int* __restrict__ csr_src,
    const int* __restrict__ cursor_end, const int* __restrict__ deg_in,
    u16* __restrict__ agg) {
  int node = blockIdx.x * 16 + (threadIdx.x >> 4);
  if (node >= NN) return;
  int q = threadIdx.x & 15;
  int end = cursor_end[node];
  int j = end - deg_in[node];
  const ushort8* Hv = (const ushort8*)H;   // row = 16 ushort8
  float a0 = 0.f, a1 = 0.f, a2 = 0.f, a3 = 0.f, a4 = 0.f, a5 = 0.f, a6 = 0.f, a7 = 0.f;
#define ACC8(v) { a0 += bf2f((v)[0]); a1 += bf2f((v)[1]); a2 += bf2f((v)[2]); a3 += bf2f((v)[3]); \
                  a4 += bf2f((v)[4]); a5 += bf2f((v)[5]); a6 += bf2f((v)[6]); a7 += bf2f((v)[7]); }
  for (; j + 4 <= end; j += 4) {
    int s0 = csr_src[j + 0];
    int s1 = csr_src[j + 1];
    int s2 = csr_src[j + 2];
    int s3 = csr_src[j + 3];
    ushort8 v0 = Hv[(size_t)s0 * 16 + q];
    ushort8 v1 = Hv[(size_t)s1 * 16 + q];
    ushort8 v2 = Hv[(size_t)s2 * 16 + q];
    ushort8 v3 = Hv[(size_t)s3 * 16 + q];
    ACC8(v0) ACC8(v1) ACC8(v2) ACC8(v3)
  }
  for (; j < end; ++j) {
    int s = csr_src[j];
    ushort8 v = Hv[(size_t)s * 16 + q];
    ACC8(v)
  }
#undef ACC8
  uint4 o;
  o.x = (unsigned)f2bf(a0) | ((unsigned)f2bf(a1) << 16);
  o.y = (unsigned)f2bf(a2) | ((unsigned)f2bf(a3) << 16);
  o.z = (unsigned)f2bf(a4) | ((unsigned)f2bf(a5) << 16);
  o.w = (unsigned)f2bf(a6) | ((unsigned)f2bf(a7) << 16);
  *(uint4*)(agg + (size_t)node * DD + q * 8) = o;
}

// C[r][c] = relu((A@W)[r][c] * rs[r] + bias[c]) * post[r], bf16 out to Cb.
__global__ __launch_bounds__(256) void gemm_mfma(
    const u16* __restrict__ Ab, const u16* __restrict__ Wt,
    const float* __restrict__ bias, const float* __restrict__ rs,
    const float* __restrict__ post, u16* __restrict__ Cb) {
  int wid = threadIdx.x >> 6;
  int lane = threadIdx.x & 63;
  int row0 = blockIdx.x * 64 + wid * 16;
  int l15 = lane & 15;
  int kg = lane >> 4;
  int arow = row0 + l15;
  bool rowok = arow < NN;
  const u16* aptr = Ab + (size_t)arow * DD + kg * 8;
  const u16* bbase = Wt + (size_t)l15 * DD + kg * 8;
  f32x4 acc[8];
#pragma unroll
  for (int n = 0; n < 8; ++n) acc[n] = (f32x4){0.f, 0.f, 0.f, 0.f};
#pragma unroll
  for (int kt = 0; kt < 4; ++kt) {
    short8 a = (short8){0, 0, 0, 0, 0, 0, 0, 0};
    if (rowok) a = *(const short8*)(aptr + kt * 32);
#pragma unroll
    for (int n = 0; n < 8; ++n) {
      short8 b = *(const short8*)(bbase + (size_t)n * 16 * DD + kt * 32);
      acc[n] = __builtin_amdgcn_mfma_f32_16x16x32_bf16(a, b, acc[n], 0, 0, 0);
    }
  }
  int crow0 = row0 + kg * 4;
#pragma unroll
  for (int j = 0; j < 4; ++j) {
    int r = crow0 + j;
    if (r < NN) {
      float s = rs[r];
      float ps = post[r];
#pragma unroll
      for (int n = 0; n < 8; ++n) {
        float v = fmaxf(acc[n][j] * s + bias[n * 16 + l15], 0.f) * ps;
        Cb[(size_t)r * DD + n * 16 + l15] = f2bf(v);
      }
    }
  }
}

// Layer-2 GEMM with pooling fused into the epilogue: no Cb output.
__global__ __launch_bounds__(256) void gemm_mfma_pool(
    const u16* __restrict__ Ab, const u16* __restrict__ Wt,
    const float* __restrict__ bias, const float* __restrict__ rs,
    const int* __restrict__ gid, float* __restrict__ pooled) {
  __shared__ float pl[NG * DD];  // 4 KB
  int tid = threadIdx.x;
  for (int i = tid; i < NG * DD; i += 256) pl[i] = 0.f;
  __syncthreads();

  int wid = tid >> 6;
  int lane = tid & 63;
  int row0 = blockIdx.x * 64 + wid * 16;
  int l15 = lane & 15;
  int kg = lane >> 4;
  int arow = row0 + l15;
  bool rowok = arow < NN;
  const u16* aptr = Ab + (size_t)arow * DD + kg * 8;
  const u16* bbase = Wt + (size_t)l15 * DD + kg * 8;
  f32x4 acc[8];
#pragma unroll
  for (int n = 0; n < 8; ++n) acc[n] = (f32x4){0.f, 0.f, 0.f, 0.f};
#pragma unroll
  for (int kt = 0; kt < 4; ++kt) {
    short8 a = (short8){0, 0, 0, 0, 0, 0, 0, 0};
    if (rowok) a = *(const short8*)(aptr + kt * 32);
#pragma unroll
    for (int n = 0; n < 8; ++n) {
      short8 b = *(const short8*)(bbase + (size_t)n * 16 * DD + kt * 32);
      acc[n] = __builtin_amdgcn_mfma_f32_16x16x32_bf16(a, b, acc[n], 0, 0, 0);
    }
  }
  int crow0 = row0 + kg * 4;
  float pacc[8];
#pragma unroll
  for (int n = 0; n < 8; ++n) pacc[n] = 0.f;
  int curg = -1;
#pragma unroll
  for (int j = 0; j < 4; ++j) {
    int r = crow0 + j;
    if (r < NN) {
      int g = gid[r];
      if (g != curg) {
        if (curg >= 0) {
#pragma unroll
          for (int n = 0; n < 8; ++n) {
            atomicAdd(&pl[curg * DD + n * 16 + l15], pacc[n]);
            pacc[n] = 0.f;
          }
        }
        curg = g;
      }
      float s = rs[r];
#pragma unroll
      for (int n = 0; n < 8; ++n)
        pacc[n] += fmaxf(acc[n][j] * s + bias[n * 16 + l15], 0.f);
    }
  }
  if (curg >= 0) {
#pragma unroll
    for (int n = 0; n < 8; ++n)
      atomicAdd(&pl[curg * DD + n * 16 + l15], pacc[n]);
  }
  __syncthreads();
  for (int i = tid; i < NG * DD; i += 256) {
    float v = pl[i];
    if (v != 0.f) atomicAdd(&pooled[i], v);
  }
}

__global__ __launch_bounds__(128) void final_kernel(const float* __restrict__ pooled,
                                                    const int* __restrict__ cnt,
                                                    const float* __restrict__ prelu_a,
                                                    const float* __restrict__ linW,
                                                    const float* __restrict__ linb,
                                                    float* __restrict__ out) {
  int t = threadIdx.x;  // 128
  __shared__ float red[2];
  float w = linW[t];
  float alpha = prelu_a[0];
  float lb = linb[0];
  for (int g = 0; g < NG; ++g) {
    float v = pooled[g * DD + t] / fmaxf((float)cnt[g], 1.f);
    v = v > 0.f ? v : alpha * v;
    float p = v * w;
#pragma unroll
    for (int off = 32; off >= 1; off >>= 1) p += __shfl_down(p, off, 64);
    if ((t & 63) == 0) red[t >> 6] = p;
    __syncthreads();
    if (t == 0) {
      float s = red[0] + red[1] + lb;
      out[g] = 1.f / (1.f + expf(-s));
    }
    __syncthreads();
  }
}

extern "C" void kernel_launch(void* const* d_in, const int* in_sizes, int n_in,
                              void* d_out, int out_size, void* d_ws, size_t ws_size,
                              hipStream_t stream) {
  const float* x   = (const float*)d_in[0];
  const int*   src = (const int*)d_in[1];
  const int*   dst = (const int*)d_in[2];
  const int*   gid = (const int*)d_in[3];
  const float* W1  = (const float*)d_in[4];
  const float* b1  = (const float*)d_in[5];
  const float* W2  = (const float*)d_in[6];
  const float* b2  = (const float*)d_in[7];
  const float* pa  = (const float*)d_in[8];
  const float* lW  = (const float*)d_in[9];
  const float* lb  = (const float*)d_in[10];
  float* out = (float*)d_out;

  char* ws = (char*)d_ws;
  size_t o = 0;
  auto alloc = [&](size_t bytes) {
    size_t r = o;
    o += (bytes + 255) & ~(size_t)255;
    return r;
  };
  int*   deg_in  = (int*)(ws + alloc((size_t)NN * 4));
  float* rs_out  = (float*)(ws + alloc((size_t)NN * 4));
  float* rs_in   = (float*)(ws + alloc((size_t)NN * 4));
  int*   countsS = (int*)(ws + alloc((size_t)SCAN_N * 4));
  int*   countsD = (int*)(ws + alloc((size_t)SCAN_N * 4));
  int*   cursor_end = (int*)(ws + alloc((size_t)NN * 4));
  u16*   recsS   = (u16*)(ws + alloc((size_t)NE * 2));
  unsigned* recsD = (unsigned*)(ws + alloc((size_t)NE * 4));
  int*   csr_src = (int*)(ws + alloc((size_t)NE * 4));
  u16*   Wt1     = (u16*)(ws + alloc((size_t)DD * DD * 2));
  u16*   Wt2     = (u16*)(ws + alloc((size_t)DD * DD * 2));
  u16*   buf1    = (u16*)(ws + alloc((size_t)NN * DD * 2));
  u16*   buf2    = (u16*)(ws + alloc((size_t)NN * DD * 2));
  u16*   buf3    = (u16*)(ws + alloc((size_t)NN * DD * 2));
  float* pooled  = (float*)(ws + alloc((size_t)(NG * DD + NG) * 4));
  int*   cnt     = (int*)(pooled + NG * DD);

  const int nblk = (NN + 255) / 256;  // 391

  fill_zero<<<2, 256, 0, stream>>>(pooled, (NG * DD + NG + 3) / 4);
  histo_gid<<<98, 256, 0, stream>>>(gid, cnt);

  // edge-array passes: bucket histograms -> scans -> record scatter
  p1_both<<<PB, 256, 0, stream>>>(src, dst, countsS, countsD);
  scan2<<<2, 256, 0, stream>>>(countsD, countsS);
  p2_both<<<PB, 256, 0, stream>>>(src, dst, countsS, countsD, recsS, recsD);
  src_p3<<<KB, 256, 0, stream>>>(recsS, countsS, rs_out);
  csr_p3<<<KB, 256, 0, stream>>>(recsD, countsD, csr_src, cursor_end, deg_in, rs_in);

  // x -> bf16 pre-scaled by rs_out; weights -> bf16 transposed
  conv_xscale<<<(NN * DD / 8 + 255) / 256, 256, 0, stream>>>(x, rs_out, buf1, NN * DD / 8);
  conv_w_transpose<<<64, 256, 0, stream>>>(W1, Wt1);
  conv_w_transpose<<<64, 256, 0, stream>>>(W2, Wt2);

  const int gablocks = (NN + 15) / 16;  // 6250
  const int gmblocks = (NN + 63) / 64;  // 1563

  // Layer 1: gather pre-scaled x; GEMM epilogue emits h1 * rs_out (feeds gather 2)
  gather_agg_bf16<<<gablocks, 256, 0, stream>>>(buf1, csr_src, cursor_end, deg_in, buf2);
  gemm_mfma<<<gmblocks, 256, 0, stream>>>(buf2, Wt1, b1, rs_in, rs_out, buf3);

  // Layer 2: gather, then GEMM with fused pooling (no feature output)
  gather_agg_bf16<<<gablocks, 256, 0, stream>>>(buf3, csr_src, cursor_end, deg_in, buf1);
  gemm_mfma_pool<<<gmblocks, 256, 0, stream>>>(buf1, Wt2, b2, rs_in, gid, pooled);

  // Head
  final_kernel<<<1, 128, 0, stream>>>(pooled, cnt, pa, lW, lb, out);
}

// Round 8
// 299.625 us; speedup vs baseline: 2.3369x; 1.1650x over previous
//
#include <hip/hip_runtime.h>
#include <hip/hip_bf16.h>

#define NN 100000
#define NE 1600000
#define DD 128
#define NG 8

#define KB 98        // node buckets (id >> 10)
#define BSH 10
#define PB 128       // phase-1/2 blocks
#define CHUNK 12500  // NE / PB exactly
#define SCAN_N (KB * PB)  // 12544

typedef unsigned short u16;
typedef unsigned char u8;
typedef __attribute__((ext_vector_type(8))) short short8;
typedef __attribute__((ext_vector_type(4))) float f32x4;
typedef __attribute__((ext_vector_type(2))) float f32x2;

static __device__ __forceinline__ float bf2f(u16 u) {
  return __uint_as_float(((unsigned)u) << 16);
}
static __device__ __forceinline__ u16 f2bf(float f) {
  unsigned u = __float_as_uint(f);
  u += 0x7fffu + ((u >> 16) & 1);
  return (u16)(u >> 16);
}
static __device__ __forceinline__ u8 f2fp8(float f) {
  return (u8)(__builtin_amdgcn_cvt_pk_fp8_f32(f, f, 0, false) & 0xFF);
}

__global__ void fill_zero(float* __restrict__ p, int n4) {
  int i = blockIdx.x * blockDim.x + threadIdx.x;
  if (i < n4) ((float4*)p)[i] = make_float4(0.f, 0.f, 0.f, 0.f);
}

// out[n][d] = fp8(x[n][d] * rs_out[n]); one thread = 8 elems -> 8 bytes
__global__ void conv_xscale(const float* __restrict__ in, const float* __restrict__ rs_out,
                            u8* __restrict__ out, int n8) {
  int i = blockIdx.x * blockDim.x + threadIdx.x;
  if (i >= n8) return;
  float w = rs_out[i >> 4];
  const float4* p = (const float4*)(in + (size_t)i * 8);
  float4 a = p[0], b = p[1];
  int lo = 0, hi = 0;
  lo = __builtin_amdgcn_cvt_pk_fp8_f32(a.x * w, a.y * w, lo, false);
  lo = __builtin_amdgcn_cvt_pk_fp8_f32(a.z * w, a.w * w, lo, true);
  hi = __builtin_amdgcn_cvt_pk_fp8_f32(b.x * w, b.y * w, hi, false);
  hi = __builtin_amdgcn_cvt_pk_fp8_f32(b.z * w, b.w * w, hi, true);
  ((uint2*)out)[i] = make_uint2((unsigned)lo, (unsigned)hi);
}

__global__ void conv_w_transpose(const float* __restrict__ W, u16* __restrict__ Wt) {
  int idx = blockIdx.x * blockDim.x + threadIdx.x;
  if (idx >= DD * DD) return;
  int n = idx >> 7, k = idx & 127;
  Wt[idx] = f2bf(W[k * DD + n]);
}

__global__ __launch_bounds__(256) void histo_gid(const int* __restrict__ gid,
                                                 int* __restrict__ cnt) {
  __shared__ int h[NG];
  int t = threadIdx.x;
  if (t < NG) h[t] = 0;
  __syncthreads();
  for (int i = blockIdx.x * 256 + t; i < NN; i += gridDim.x * 256)
    atomicAdd(&h[gid[i]], 1);
  __syncthreads();
  if (t < NG && h[t]) atomicAdd(&cnt[t], h[t]);
}

// ---- combined bucket histograms for src and dst ----
__global__ __launch_bounds__(256) void p1_both(const int* __restrict__ src,
                                               const int* __restrict__ dst,
                                               int* __restrict__ countsS,
                                               int* __restrict__ countsD) {
  __shared__ int hs[KB], hd[KB];
  int t = threadIdx.x, blk = blockIdx.x;
  for (int i = t; i < KB; i += 256) { hs[i] = 0; hd[i] = 0; }
  __syncthreads();
  int e0 = blk * CHUNK;
  for (int i = t; i < CHUNK; i += 256) {
    atomicAdd(&hs[src[e0 + i] >> BSH], 1);
    atomicAdd(&hd[dst[e0 + i] >> BSH], 1);
  }
  __syncthreads();
  for (int i = t; i < KB; i += 256) {
    countsS[i * PB + blk] = hs[i];
    countsD[i * PB + blk] = hd[i];
  }
}

// grid=2: block 0 scans countsD, block 1 scans countsS (exclusive, in place)
__global__ __launch_bounds__(256) void scan2(int* __restrict__ countsD,
                                             int* __restrict__ countsS) {
  __shared__ int data[SCAN_N];   // 50 KB
  __shared__ int part[256];
  int* counts = (blockIdx.x == 0) ? countsD : countsS;
  int t = threadIdx.x;
  const int per = (SCAN_N + 255) / 256;  // 49
  for (int i = t; i < SCAN_N; i += 256) data[i] = counts[i];
  __syncthreads();
  int base = t * per;
  int s = 0;
  for (int i = 0; i < per; ++i) {
    int idx = base + i;
    if (idx < SCAN_N) s += data[idx];
  }
  part[t] = s;
  __syncthreads();
  for (int off = 1; off < 256; off <<= 1) {
    int v = (t >= off) ? part[t - off] : 0;
    __syncthreads();
    part[t] += v;
    __syncthreads();
  }
  int run = (t == 0) ? 0 : part[t - 1];
  for (int i = 0; i < per; ++i) {
    int idx = base + i;
    if (idx < SCAN_N) {
      int v = data[idx];
      data[idx] = run;
      run += v;
    }
  }
  __syncthreads();
  for (int i = t; i < SCAN_N; i += 256) counts[i] = data[i];
}

// combined scatter: recsD (u32, CSR records) + recsS (u16, src low bits)
__global__ __launch_bounds__(256) void p2_both(const int* __restrict__ src,
                                               const int* __restrict__ dst,
                                               const int* __restrict__ scS,
                                               const int* __restrict__ scD,
                                               u16* __restrict__ recsS,
                                               unsigned* __restrict__ recsD) {
  __shared__ int curS[KB], curD[KB];
  int t = threadIdx.x, blk = blockIdx.x;
  for (int i = t; i < KB; i += 256) {
    curS[i] = scS[i * PB + blk];
    curD[i] = scD[i * PB + blk];
  }
  __syncthreads();
  int e0 = blk * CHUNK;
  for (int i = t; i < CHUNK; i += 256) {
    int s = src[e0 + i];
    int d = dst[e0 + i];
    int ps = atomicAdd(&curS[s >> BSH], 1);
    recsS[ps] = (u16)(s & ((1 << BSH) - 1));
    int pd = atomicAdd(&curD[d >> BSH], 1);
    recsD[pd] = (unsigned)s | ((unsigned)(d & ((1 << BSH) - 1)) << 17);
  }
}

// per src-bucket histogram -> rs_out (no deg_out array)
__global__ __launch_bounds__(256) void src_p3(const u16* __restrict__ recsS,
                                              const int* __restrict__ scS,
                                              float* __restrict__ rs_out) {
  __shared__ int hist[1 << BSH];
  int k = blockIdx.x, t = threadIdx.x;
  int rbeg = scS[k * PB];
  int rend = (k < KB - 1) ? scS[(k + 1) * PB] : NE;
  for (int i = t; i < (1 << BSH); i += 256) hist[i] = 0;
  __syncthreads();
  for (int i = rbeg + t; i < rend; i += 256) atomicAdd(&hist[recsS[i]], 1);
  __syncthreads();
  int nbase = k << BSH;
  for (int i = t; i < (1 << BSH); i += 256) {
    int n = nbase + i;
    if (n < NN) rs_out[n] = rsqrtf(fmaxf((float)hist[i], 1.f));
  }
}

// One block per dst bucket: deg_in/rs_in/cursor_end + ordered csr scatter.
__global__ __launch_bounds__(256) void csr_p3(const unsigned* __restrict__ recs,
                                              const int* __restrict__ scanned,
                                              int* __restrict__ csr_src,
                                              int* __restrict__ cursor_end,
                                              int* __restrict__ deg_in,
                                              float* __restrict__ rs_in) {
  __shared__ int hist[1 << BSH];  // 1024
  __shared__ int part[256];
  int k = blockIdx.x, t = threadIdx.x;
  int rbeg = scanned[k * PB];
  int rend = (k < KB - 1) ? scanned[(k + 1) * PB] : NE;
  int nbase = k << BSH;
  for (int i = t; i < (1 << BSH); i += 256) hist[i] = 0;
  __syncthreads();
  for (int i = rbeg + t; i < rend; i += 256) atomicAdd(&hist[recs[i] >> 17], 1);
  __syncthreads();
  int h[4];
#pragma unroll
  for (int j = 0; j < 4; ++j) h[j] = hist[t * 4 + j];
  part[t] = h[0] + h[1] + h[2] + h[3];
  __syncthreads();
  for (int off = 1; off < 256; off <<= 1) {
    int v = (t >= off) ? part[t - off] : 0;
    __syncthreads();
    part[t] += v;
    __syncthreads();
  }
  int run = rbeg + ((t == 0) ? 0 : part[t - 1]);
#pragma unroll
  for (int j = 0; j < 4; ++j) {
    int n = nbase + t * 4 + j;
    if (n < NN) {
      cursor_end[n] = run + h[j];
      deg_in[n] = h[j];
      rs_in[n] = rsqrtf(fmaxf((float)h[j], 1.f));
    }
    hist[t * 4 + j] = run;   // running write cursor (start)
    run += h[j];
  }
  __syncthreads();
  for (int i = rbeg + t; i < rend; i += 256) {
    unsigned r = recs[i];
    int pos = atomicAdd(&hist[r >> 17], 1);
    csr_src[pos] = (int)(r & 0x1FFFF);
  }
}

// One 8-lane group per dst node; lane q covers fp8 elems 16q..16q+15 (16B).
// H rows are fp8, PRE-SCALED by rs_out. Accumulate fp32, emit bf16.
__global__ __launch_bounds__(256) void gather_agg_fp8(
    const uint4* __restrict__ Hv, const int* __restrict__ csr_src,
    const int* __restrict__ cursor_end, const int* __restrict__ deg_in,
    u16* __restrict__ agg) {
  int node = blockIdx.x * 32 + (threadIdx.x >> 3);
  if (node >= NN) return;
  int q = threadIdx.x & 7;
  int end = cursor_end[node];
  int j = end - deg_in[node];
  float acc[16];
#pragma unroll
  for (int i = 0; i < 16; ++i) acc[i] = 0.f;
#define ACCV(v) { f32x2 t_;                                                        \
  t_ = __builtin_amdgcn_cvt_pk_f32_fp8((int)(v).x, false); acc[0] += t_.x;  acc[1] += t_.y;  \
  t_ = __builtin_amdgcn_cvt_pk_f32_fp8((int)(v).x, true);  acc[2] += t_.x;  acc[3] += t_.y;  \
  t_ = __builtin_amdgcn_cvt_pk_f32_fp8((int)(v).y, false); acc[4] += t_.x;  acc[5] += t_.y;  \
  t_ = __builtin_amdgcn_cvt_pk_f32_fp8((int)(v).y, true);  acc[6] += t_.x;  acc[7] += t_.y;  \
  t_ = __builtin_amdgcn_cvt_pk_f32_fp8((int)(v).z, false); acc[8] += t_.x;  acc[9] += t_.y;  \
  t_ = __builtin_amdgcn_cvt_pk_f32_fp8((int)(v).z, true);  acc[10] += t_.x; acc[11] += t_.y; \
  t_ = __builtin_amdgcn_cvt_pk_f32_fp8((int)(v).w, false); acc[12] += t_.x; acc[13] += t_.y; \
  t_ = __builtin_amdgcn_cvt_pk_f32_fp8((int)(v).w, true);  acc[14] += t_.x; acc[15] += t_.y; }
  for (; j + 4 <= end; j += 4) {
    int s0 = csr_src[j + 0];
    int s1 = csr_src[j + 1];
    int s2 = csr_src[j + 2];
    int s3 = csr_src[j + 3];
    uint4 v0 = Hv[(size_t)s0 * 8 + q];
    uint4 v1 = Hv[(size_t)s1 * 8 + q];
    uint4 v2 = Hv[(size_t)s2 * 8 + q];
    uint4 v3 = Hv[(size_t)s3 * 8 + q];
    ACCV(v0) ACCV(v1) ACCV(v2) ACCV(v3)
  }
  for (; j < end; ++j) {
    uint4 v = Hv[(size_t)csr_src[j] * 8 + q];
    ACCV(v)
  }
#undef ACCV
  uint4 o0, o1;
  o0.x = (unsigned)f2bf(acc[0])  | ((unsigned)f2bf(acc[1])  << 16);
  o0.y = (unsigned)f2bf(acc[2])  | ((unsigned)f2bf(acc[3])  << 16);
  o0.z = (unsigned)f2bf(acc[4])  | ((unsigned)f2bf(acc[5])  << 16);
  o0.w = (unsigned)f2bf(acc[6])  | ((unsigned)f2bf(acc[7])  << 16);
  o1.x = (unsigned)f2bf(acc[8])  | ((unsigned)f2bf(acc[9])  << 16);
  o1.y = (unsigned)f2bf(acc[10]) | ((unsigned)f2bf(acc[11]) << 16);
  o1.z = (unsigned)f2bf(acc[12]) | ((unsigned)f2bf(acc[13]) << 16);
  o1.w = (unsigned)f2bf(acc[14]) | ((unsigned)f2bf(acc[15]) << 16);
  u16* op = agg + (size_t)node * DD + q * 16;
  *(uint4*)op = o0;
  *(uint4*)(op + 8) = o1;
}

// C[r][c] = fp8( relu((A@W)[r][c] * rs[r] + bias[c]) * post[r] ), byte out.
__global__ __launch_bounds__(256) void gemm_mfma_fp8out(
    const u16* __restrict__ Ab, const u16* __restrict__ Wt,
    const float* __restrict__ bias, const float* __restrict__ rs,
    const float* __restrict__ post, u8* __restrict__ Cb) {
  int wid = threadIdx.x >> 6;
  int lane = threadIdx.x & 63;
  int row0 = blockIdx.x * 64 + wid * 16;
  int l15 = lane & 15;
  int kg = lane >> 4;
  int arow = row0 + l15;
  bool rowok = arow < NN;
  const u16* aptr = Ab + (size_t)arow * DD + kg * 8;
  const u16* bbase = Wt + (size_t)l15 * DD + kg * 8;
  f32x4 acc[8];
#pragma unroll
  for (int n = 0; n < 8; ++n) acc[n] = (f32x4){0.f, 0.f, 0.f, 0.f};
#pragma unroll
  for (int kt = 0; kt < 4; ++kt) {
    short8 a = (short8){0, 0, 0, 0, 0, 0, 0, 0};
    if (rowok) a = *(const short8*)(aptr + kt * 32);
#pragma unroll
    for (int n = 0; n < 8; ++n) {
      short8 b = *(const short8*)(bbase + (size_t)n * 16 * DD + kt * 32);
      acc[n] = __builtin_amdgcn_mfma_f32_16x16x32_bf16(a, b, acc[n], 0, 0, 0);
    }
  }
  int crow0 = row0 + kg * 4;
#pragma unroll
  for (int j = 0; j < 4; ++j) {
    int r = crow0 + j;
    if (r < NN) {
      float s = rs[r];
      float ps = post[r];
#pragma unroll
      for (int n = 0; n < 8; ++n) {
        float v = fmaxf(acc[n][j] * s + bias[n * 16 + l15], 0.f) * ps;
        Cb[(size_t)r * DD + n * 16 + l15] = f2fp8(v);
      }
    }
  }
}

// Layer-2 GEMM with pooling fused into the epilogue: no feature output.
__global__ __launch_bounds__(256) void gemm_mfma_pool(
    const u16* __restrict__ Ab, const u16* __restrict__ Wt,
    const float* __restrict__ bias, const float* __restrict__ rs,
    const int* __restrict__ gid, float* __restrict__ pooled) {
  __shared__ float pl[NG * DD];  // 4 KB
  int tid = threadIdx.x;
  for (int i = tid; i < NG * DD; i += 256) pl[i] = 0.f;
  __syncthreads();

  int wid = tid >> 6;
  int lane = tid & 63;
  int row0 = blockIdx.x * 64 + wid * 16;
  int l15 = lane & 15;
  int kg = lane >> 4;
  int arow = row0 + l15;
  bool rowok = arow < NN;
  const u16* aptr = Ab + (size_t)arow * DD + kg * 8;
  const u16* bbase = Wt + (size_t)l15 * DD + kg * 8;
  f32x4 acc[8];
#pragma unroll
  for (int n = 0; n < 8; ++n) acc[n] = (f32x4){0.f, 0.f, 0.f, 0.f};
#pragma unroll
  for (int kt = 0; kt < 4; ++kt) {
    short8 a = (short8){0, 0, 0, 0, 0, 0, 0, 0};
    if (rowok) a = *(const short8*)(aptr + kt * 32);
#pragma unroll
    for (int n = 0; n < 8; ++n) {
      short8 b = *(const short8*)(bbase + (size_t)n * 16 * DD + kt * 32);
      acc[n] = __builtin_amdgcn_mfma_f32_16x16x32_bf16(a, b, acc[n], 0, 0, 0);
    }
  }
  int crow0 = row0 + kg * 4;
  float pacc[8];
#pragma unroll
  for (int n = 0; n < 8; ++n) pacc[n] = 0.f;
  int curg = -1;
#pragma unroll
  for (int j = 0; j < 4; ++j) {
    int r = crow0 + j;
    if (r < NN) {
      int g = gid[r];
      if (g != curg) {
        if (curg >= 0) {
#pragma unroll
          for (int n = 0; n < 8; ++n) {
            atomicAdd(&pl[curg * DD + n * 16 + l15], pacc[n]);
            pacc[n] = 0.f;
          }
        }
        curg = g;
      }
      float s = rs[r];
#pragma unroll
      for (int n = 0; n < 8; ++n)
        pacc[n] += fmaxf(acc[n][j] * s + bias[n * 16 + l15], 0.f);
    }
  }
  if (curg >= 0) {
#pragma unroll
    for (int n = 0; n < 8; ++n)
      atomicAdd(&pl[curg * DD + n * 16 + l15], pacc[n]);
  }
  __syncthreads();
  for (int i = tid; i < NG * DD; i += 256) {
    float v = pl[i];
    if (v != 0.f) atomicAdd(&pooled[i], v);
  }
}

__global__ __launch_bounds__(128) void final_kernel(const float* __restrict__ pooled,
                                                    const int* __restrict__ cnt,
                                                    const float* __restrict__ prelu_a,
                                                    const float* __restrict__ linW,
                                                    const float* __restrict__ linb,
                                                    float* __restrict__ out) {
  int t = threadIdx.x;  // 128
  __shared__ float red[2];
  float w = linW[t];
  float alpha = prelu_a[0];
  float lb = linb[0];
  for (int g = 0; g < NG; ++g) {
    float v = pooled[g * DD + t] / fmaxf((float)cnt[g], 1.f);
    v = v > 0.f ? v : alpha * v;
    float p = v * w;
#pragma unroll
    for (int off = 32; off >= 1; off >>= 1) p += __shfl_down(p, off, 64);
    if ((t & 63) == 0) red[t >> 6] = p;
    __syncthreads();
    if (t == 0) {
      float s = red[0] + red[1] + lb;
      out[g] = 1.f / (1.f + expf(-s));
    }
    __syncthreads();
  }
}

extern "C" void kernel_launch(void* const* d_in, const int* in_sizes, int n_in,
                              void* d_out, int out_size, void* d_ws, size_t ws_size,
                              hipStream_t stream) {
  const float* x   = (const float*)d_in[0];
  const int*   src = (const int*)d_in[1];
  const int*   dst = (const int*)d_in[2];
  const int*   gid = (const int*)d_in[3];
  const float* W1  = (const float*)d_in[4];
  const float* b1  = (const float*)d_in[5];
  const float* W2  = (const float*)d_in[6];
  const float* b2  = (const float*)d_in[7];
  const float* pa  = (const float*)d_in[8];
  const float* lW  = (const float*)d_in[9];
  const float* lb  = (const float*)d_in[10];
  float* out = (float*)d_out;

  char* ws = (char*)d_ws;
  size_t o = 0;
  auto alloc = [&](size_t bytes) {
    size_t r = o;
    o += (bytes + 255) & ~(size_t)255;
    return r;
  };
  int*   deg_in  = (int*)(ws + alloc((size_t)NN * 4));
  float* rs_out  = (float*)(ws + alloc((size_t)NN * 4));
  float* rs_in   = (float*)(ws + alloc((size_t)NN * 4));
  int*   countsS = (int*)(ws + alloc((size_t)SCAN_N * 4));
  int*   countsD = (int*)(ws + alloc((size_t)SCAN_N * 4));
  int*   cursor_end = (int*)(ws + alloc((size_t)NN * 4));
  u16*   recsS   = (u16*)(ws + alloc((size_t)NE * 2));
  unsigned* recsD = (unsigned*)(ws + alloc((size_t)NE * 4));
  int*   csr_src = (int*)(ws + alloc((size_t)NE * 4));
  u16*   Wt1     = (u16*)(ws + alloc((size_t)DD * DD * 2));
  u16*   Wt2     = (u16*)(ws + alloc((size_t)DD * DD * 2));
  u8*    bufA    = (u8*)(ws + alloc((size_t)NN * DD));      // fp8 layer-1 input
  u8*    bufB    = (u8*)(ws + alloc((size_t)NN * DD));      // fp8 layer-2 input
  u16*   aggbuf  = (u16*)(ws + alloc((size_t)NN * DD * 2)); // bf16 agg
  float* pooled  = (float*)(ws + alloc((size_t)(NG * DD + NG) * 4));
  int*   cnt     = (int*)(pooled + NG * DD);

  fill_zero<<<2, 256, 0, stream>>>(pooled, (NG * DD + NG + 3) / 4);
  histo_gid<<<98, 256, 0, stream>>>(gid, cnt);

  // edge-array passes: bucket histograms -> scans -> record scatter
  p1_both<<<PB, 256, 0, stream>>>(src, dst, countsS, countsD);
  scan2<<<2, 256, 0, stream>>>(countsD, countsS);
  p2_both<<<PB, 256, 0, stream>>>(src, dst, countsS, countsD, recsS, recsD);
  src_p3<<<KB, 256, 0, stream>>>(recsS, countsS, rs_out);
  csr_p3<<<KB, 256, 0, stream>>>(recsD, countsD, csr_src, cursor_end, deg_in, rs_in);

  // x -> fp8 pre-scaled by rs_out; weights -> bf16 transposed
  conv_xscale<<<(NN * DD / 8 + 255) / 256, 256, 0, stream>>>(x, rs_out, bufA, NN * DD / 8);
  conv_w_transpose<<<64, 256, 0, stream>>>(W1, Wt1);
  conv_w_transpose<<<64, 256, 0, stream>>>(W2, Wt2);

  const int gablocks = (NN + 31) / 32;  // 3125
  const int gmblocks = (NN + 63) / 64;  // 1563

  // Layer 1: gather fp8 x-scaled; GEMM epilogue emits fp8 h1*rs_out
  gather_agg_fp8<<<gablocks, 256, 0, stream>>>((const uint4*)bufA, csr_src, cursor_end, deg_in, aggbuf);
  gemm_mfma_fp8out<<<gmblocks, 256, 0, stream>>>(aggbuf, Wt1, b1, rs_in, rs_out, bufB);

  // Layer 2: gather fp8, then GEMM with fused pooling
  gather_agg_fp8<<<gablocks, 256, 0, stream>>>((const uint4*)bufB, csr_src, cursor_end, deg_in, aggbuf);
  gemm_mfma_pool<<<gmblocks, 256, 0, stream>>>(aggbuf, Wt2, b2, rs_in, gid, pooled);

  // Head
  final_kernel<<<1, 128, 0, stream>>>(pooled, cnt, pa, lW, lb, out);
}

// Round 9
// 249.246 us; speedup vs baseline: 2.8092x; 1.2021x over previous
//
#include <hip/hip_runtime.h>
#include <hip/hip_bf16.h>

#define NN 100000
#define NE 1600000
#define DD 128
#define NG 8

#define KB 98        // node buckets (id >> 10)
#define BSH 10
#define PB 128       // phase-1/2 blocks
#define CHUNK 12500  // NE / PB exactly
#define SCAN_N (KB * PB)  // 12544

typedef unsigned short u16;
typedef unsigned char u8;
typedef __attribute__((ext_vector_type(8))) short short8;
typedef __attribute__((ext_vector_type(4))) float f32x4;
typedef __attribute__((ext_vector_type(2))) float f32x2;

static __device__ __forceinline__ float bf2f(u16 u) {
  return __uint_as_float(((unsigned)u) << 16);
}
static __device__ __forceinline__ u16 f2bf(float f) {
  unsigned u = __float_as_uint(f);
  u += 0x7fffu + ((u >> 16) & 1);
  return (u16)(u >> 16);
}
static __device__ __forceinline__ u8 f2fp8(float f) {
  return (u8)(__builtin_amdgcn_cvt_pk_fp8_f32(f, f, 0, false) & 0xFF);
}

__global__ void fill_zero(float* __restrict__ p, int n4) {
  int i = blockIdx.x * blockDim.x + threadIdx.x;
  if (i < n4) ((float4*)p)[i] = make_float4(0.f, 0.f, 0.f, 0.f);
}

// out[n][d] = fp8(x[n][d] * rs_out[n]); one thread = 8 elems -> 8 bytes
__global__ void conv_xscale(const float* __restrict__ in, const float* __restrict__ rs_out,
                            u8* __restrict__ out, int n8) {
  int i = blockIdx.x * blockDim.x + threadIdx.x;
  if (i >= n8) return;
  float w = rs_out[i >> 4];
  const float4* p = (const float4*)(in + (size_t)i * 8);
  float4 a = p[0], b = p[1];
  int lo = 0, hi = 0;
  lo = __builtin_amdgcn_cvt_pk_fp8_f32(a.x * w, a.y * w, lo, false);
  lo = __builtin_amdgcn_cvt_pk_fp8_f32(a.z * w, a.w * w, lo, true);
  hi = __builtin_amdgcn_cvt_pk_fp8_f32(b.x * w, b.y * w, hi, false);
  hi = __builtin_amdgcn_cvt_pk_fp8_f32(b.z * w, b.w * w, hi, true);
  ((uint2*)out)[i] = make_uint2((unsigned)lo, (unsigned)hi);
}

__global__ void conv_w_transpose(const float* __restrict__ W, u16* __restrict__ Wt) {
  int idx = blockIdx.x * blockDim.x + threadIdx.x;
  if (idx >= DD * DD) return;
  int n = idx >> 7, k = idx & 127;
  Wt[idx] = f2bf(W[k * DD + n]);
}

__global__ __launch_bounds__(256) void histo_gid(const int* __restrict__ gid,
                                                 int* __restrict__ cnt) {
  __shared__ int h[NG];
  int t = threadIdx.x;
  if (t < NG) h[t] = 0;
  __syncthreads();
  for (int i = blockIdx.x * 256 + t; i < NN; i += gridDim.x * 256)
    atomicAdd(&h[gid[i]], 1);
  __syncthreads();
  if (t < NG && h[t]) atomicAdd(&cnt[t], h[t]);
}

// ---- combined bucket histograms for src and dst ----
__global__ __launch_bounds__(256) void p1_both(const int* __restrict__ src,
                                               const int* __restrict__ dst,
                                               int* __restrict__ countsS,
                                               int* __restrict__ countsD) {
  __shared__ int hs[KB], hd[KB];
  int t = threadIdx.x, blk = blockIdx.x;
  for (int i = t; i < KB; i += 256) { hs[i] = 0; hd[i] = 0; }
  __syncthreads();
  int e0 = blk * CHUNK;
  for (int i = t; i < CHUNK; i += 256) {
    atomicAdd(&hs[src[e0 + i] >> BSH], 1);
    atomicAdd(&hd[dst[e0 + i] >> BSH], 1);
  }
  __syncthreads();
  for (int i = t; i < KB; i += 256) {
    countsS[i * PB + blk] = hs[i];
    countsD[i * PB + blk] = hd[i];
  }
}

// grid=2: block 0 scans countsD, block 1 scans countsS (exclusive, in place)
__global__ __launch_bounds__(256) void scan2(int* __restrict__ countsD,
                                             int* __restrict__ countsS) {
  __shared__ int data[SCAN_N];   // 50 KB
  __shared__ int part[256];
  int* counts = (blockIdx.x == 0) ? countsD : countsS;
  int t = threadIdx.x;
  const int per = (SCAN_N + 255) / 256;  // 49
  for (int i = t; i < SCAN_N; i += 256) data[i] = counts[i];
  __syncthreads();
  int base = t * per;
  int s = 0;
  for (int i = 0; i < per; ++i) {
    int idx = base + i;
    if (idx < SCAN_N) s += data[idx];
  }
  part[t] = s;
  __syncthreads();
  for (int off = 1; off < 256; off <<= 1) {
    int v = (t >= off) ? part[t - off] : 0;
    __syncthreads();
    part[t] += v;
    __syncthreads();
  }
  int run = (t == 0) ? 0 : part[t - 1];
  for (int i = 0; i < per; ++i) {
    int idx = base + i;
    if (idx < SCAN_N) {
      int v = data[idx];
      data[idx] = run;
      run += v;
    }
  }
  __syncthreads();
  for (int i = t; i < SCAN_N; i += 256) counts[i] = data[i];
}

// combined scatter: recsD (u32, CSR records) + recsS (u16, src low bits)
__global__ __launch_bounds__(256) void p2_both(const int* __restrict__ src,
                                               const int* __restrict__ dst,
                                               const int* __restrict__ scS,
                                               const int* __restrict__ scD,
                                               u16* __restrict__ recsS,
                                               unsigned* __restrict__ recsD) {
  __shared__ int curS[KB], curD[KB];
  int t = threadIdx.x, blk = blockIdx.x;
  for (int i = t; i < KB; i += 256) {
    curS[i] = scS[i * PB + blk];
    curD[i] = scD[i * PB + blk];
  }
  __syncthreads();
  int e0 = blk * CHUNK;
  for (int i = t; i < CHUNK; i += 256) {
    int s = src[e0 + i];
    int d = dst[e0 + i];
    int ps = atomicAdd(&curS[s >> BSH], 1);
    recsS[ps] = (u16)(s & ((1 << BSH) - 1));
    int pd = atomicAdd(&curD[d >> BSH], 1);
    recsD[pd] = (unsigned)s | ((unsigned)(d & ((1 << BSH) - 1)) << 17);
  }
}

// per src-bucket histogram -> rs_out (no deg_out array)
__global__ __launch_bounds__(256) void src_p3(const u16* __restrict__ recsS,
                                              const int* __restrict__ scS,
                                              float* __restrict__ rs_out) {
  __shared__ int hist[1 << BSH];
  int k = blockIdx.x, t = threadIdx.x;
  int rbeg = scS[k * PB];
  int rend = (k < KB - 1) ? scS[(k + 1) * PB] : NE;
  for (int i = t; i < (1 << BSH); i += 256) hist[i] = 0;
  __syncthreads();
  for (int i = rbeg + t; i < rend; i += 256) atomicAdd(&hist[recsS[i]], 1);
  __syncthreads();
  int nbase = k << BSH;
  for (int i = t; i < (1 << BSH); i += 256) {
    int n = nbase + i;
    if (n < NN) rs_out[n] = rsqrtf(fmaxf((float)hist[i], 1.f));
  }
}

// One block per dst bucket: deg_in/rs_in/cursor_end + ordered csr scatter.
__global__ __launch_bounds__(256) void csr_p3(const unsigned* __restrict__ recs,
                                              const int* __restrict__ scanned,
                                              int* __restrict__ csr_src,
                                              int* __restrict__ cursor_end,
                                              int* __restrict__ deg_in,
                                              float* __restrict__ rs_in) {
  __shared__ int hist[1 << BSH];  // 1024
  __shared__ int part[256];
  int k = blockIdx.x, t = threadIdx.x;
  int rbeg = scanned[k * PB];
  int rend = (k < KB - 1) ? scanned[(k + 1) * PB] : NE;
  int nbase = k << BSH;
  for (int i = t; i < (1 << BSH); i += 256) hist[i] = 0;
  __syncthreads();
  for (int i = rbeg + t; i < rend; i += 256) atomicAdd(&hist[recs[i] >> 17], 1);
  __syncthreads();
  int h[4];
#pragma unroll
  for (int j = 0; j < 4; ++j) h[j] = hist[t * 4 + j];
  part[t] = h[0] + h[1] + h[2] + h[3];
  __syncthreads();
  for (int off = 1; off < 256; off <<= 1) {
    int v = (t >= off) ? part[t - off] : 0;
    __syncthreads();
    part[t] += v;
    __syncthreads();
  }
  int run = rbeg + ((t == 0) ? 0 : part[t - 1]);
#pragma unroll
  for (int j = 0; j < 4; ++j) {
    int n = nbase + t * 4 + j;
    if (n < NN) {
      cursor_end[n] = run + h[j];
      deg_in[n] = h[j];
      rs_in[n] = rsqrtf(fmaxf((float)h[j], 1.f));
    }
    hist[t * 4 + j] = run;   // running write cursor (start)
    run += h[j];
  }
  __syncthreads();
  for (int i = rbeg + t; i < rend; i += 256) {
    unsigned r = recs[i];
    int pos = atomicAdd(&hist[r >> 17], 1);
    csr_src[pos] = (int)(r & 0x1FFFF);
  }
}

// One 8-lane group per dst node; lane q covers fp8 elems 16q..16q+15 (16B).
__global__ __launch_bounds__(256) void gather_agg_fp8(
    const uint4* __restrict__ Hv, const int* __restrict__ csr_src,
    const int* __restrict__ cursor_end, const int* __restrict__ deg_in,
    u16* __restrict__ agg) {
  int node = blockIdx.x * 32 + (threadIdx.x >> 3);
  if (node >= NN) return;
  int q = threadIdx.x & 7;
  int end = cursor_end[node];
  int j = end - deg_in[node];
  float acc[16];
#pragma unroll
  for (int i = 0; i < 16; ++i) acc[i] = 0.f;
#define ACCV(v) { f32x2 t_;                                                        \
  t_ = __builtin_amdgcn_cvt_pk_f32_fp8((int)(v).x, false); acc[0] += t_.x;  acc[1] += t_.y;  \
  t_ = __builtin_amdgcn_cvt_pk_f32_fp8((int)(v).x, true);  acc[2] += t_.x;  acc[3] += t_.y;  \
  t_ = __builtin_amdgcn_cvt_pk_f32_fp8((int)(v).y, false); acc[4] += t_.x;  acc[5] += t_.y;  \
  t_ = __builtin_amdgcn_cvt_pk_f32_fp8((int)(v).y, true);  acc[6] += t_.x;  acc[7] += t_.y;  \
  t_ = __builtin_amdgcn_cvt_pk_f32_fp8((int)(v).z, false); acc[8] += t_.x;  acc[9] += t_.y;  \
  t_ = __builtin_amdgcn_cvt_pk_f32_fp8((int)(v).z, true);  acc[10] += t_.x; acc[11] += t_.y; \
  t_ = __builtin_amdgcn_cvt_pk_f32_fp8((int)(v).w, false); acc[12] += t_.x; acc[13] += t_.y; \
  t_ = __builtin_amdgcn_cvt_pk_f32_fp8((int)(v).w, true);  acc[14] += t_.x; acc[15] += t_.y; }
  for (; j + 4 <= end; j += 4) {
    int s0 = csr_src[j + 0];
    int s1 = csr_src[j + 1];
    int s2 = csr_src[j + 2];
    int s3 = csr_src[j + 3];
    uint4 v0 = Hv[(size_t)s0 * 8 + q];
    uint4 v1 = Hv[(size_t)s1 * 8 + q];
    uint4 v2 = Hv[(size_t)s2 * 8 + q];
    uint4 v3 = Hv[(size_t)s3 * 8 + q];
    ACCV(v0) ACCV(v1) ACCV(v2) ACCV(v3)
  }
  for (; j < end; ++j) {
    uint4 v = Hv[(size_t)csr_src[j] * 8 + q];
    ACCV(v)
  }
#undef ACCV
  uint4 o0, o1;
  o0.x = (unsigned)f2bf(acc[0])  | ((unsigned)f2bf(acc[1])  << 16);
  o0.y = (unsigned)f2bf(acc[2])  | ((unsigned)f2bf(acc[3])  << 16);
  o0.z = (unsigned)f2bf(acc[4])  | ((unsigned)f2bf(acc[5])  << 16);
  o0.w = (unsigned)f2bf(acc[6])  | ((unsigned)f2bf(acc[7])  << 16);
  o1.x = (unsigned)f2bf(acc[8])  | ((unsigned)f2bf(acc[9])  << 16);
  o1.y = (unsigned)f2bf(acc[10]) | ((unsigned)f2bf(acc[11]) << 16);
  o1.z = (unsigned)f2bf(acc[12]) | ((unsigned)f2bf(acc[13]) << 16);
  o1.w = (unsigned)f2bf(acc[14]) | ((unsigned)f2bf(acc[15]) << 16);
  u16* op = agg + (size_t)node * DD + q * 16;
  *(uint4*)op = o0;
  *(uint4*)(op + 8) = o1;
}

// ---- LDS-staged GEMM core ----
// Wt staged in 32 KB LDS, XOR-swizzled (16B-chunk c ^= row&15). 128 rows/block,
// 4 waves x 2 row-tiles of 16. b fragment read once -> feeds both tiles' MFMAs.
#define GEMM_PRE                                                              \
  __shared__ uint4 Wl4[2048]; /* 32 KB */                                     \
  int tid = threadIdx.x;                                                      \
  {                                                                           \
    const uint4* Wg4 = (const uint4*)Wt;                                      \
    for (int i = tid; i < 2048; i += 256) {                                   \
      int row = i >> 4, c = i & 15;                                           \
      Wl4[(row << 4) | (c ^ (row & 15))] = Wg4[i];                            \
    }                                                                         \
  }                                                                           \
  int wid = tid >> 6;                                                         \
  int lane = tid & 63;                                                        \
  int l15 = lane & 15;                                                        \
  int kg = lane >> 4;                                                         \
  int rowbase = blockIdx.x * 128 + wid * 32;                                  \
  f32x4 acc[2][8];                                                            \
  short8 a[2][4];                                                             \
  _Pragma("unroll")                                                           \
  for (int t = 0; t < 2; ++t) {                                               \
    int arow = rowbase + t * 16 + l15;                                        \
    bool ok = arow < NN;                                                      \
    const u16* aptr = Ab + (size_t)arow * DD + kg * 8;                        \
    _Pragma("unroll")                                                         \
    for (int kt = 0; kt < 4; ++kt) {                                          \
      a[t][kt] = ok ? *(const short8*)(aptr + kt * 32)                        \
                    : (short8){0, 0, 0, 0, 0, 0, 0, 0};                       \
      acc[0][kt] = (f32x4){0.f, 0.f, 0.f, 0.f};                               \
      acc[0][kt + 4] = (f32x4){0.f, 0.f, 0.f, 0.f};                           \
      acc[1][kt] = (f32x4){0.f, 0.f, 0.f, 0.f};                               \
      acc[1][kt + 4] = (f32x4){0.f, 0.f, 0.f, 0.f};                           \
    }                                                                         \
  }                                                                           \
  __syncthreads();                                                            \
  _Pragma("unroll")                                                           \
  for (int n = 0; n < 8; ++n) {                                               \
    _Pragma("unroll")                                                         \
    for (int kt = 0; kt < 4; ++kt) {                                          \
      short8 b = *(const short8*)(Wl4 + (((n * 16 + l15) << 4) |              \
                                         ((kg + kt * 4) ^ l15)));             \
      acc[0][n] = __builtin_amdgcn_mfma_f32_16x16x32_bf16(a[0][kt], b, acc[0][n], 0, 0, 0); \
      acc[1][n] = __builtin_amdgcn_mfma_f32_16x16x32_bf16(a[1][kt], b, acc[1][n], 0, 0, 0); \
    }                                                                         \
  }

// C = fp8( relu((A@W)*rs + bias) * post ), byte out.
__global__ __launch_bounds__(256) void gemm_mfma_fp8out(
    const u16* __restrict__ Ab, const u16* __restrict__ Wt,
    const float* __restrict__ bias, const float* __restrict__ rs,
    const float* __restrict__ post, u8* __restrict__ Cb) {
  GEMM_PRE
#pragma unroll
  for (int t = 0; t < 2; ++t) {
    int crow0 = rowbase + t * 16 + kg * 4;
#pragma unroll
    for (int j = 0; j < 4; ++j) {
      int r = crow0 + j;
      if (r < NN) {
        float s = rs[r];
        float ps = post[r];
#pragma unroll
        for (int n = 0; n < 8; ++n) {
          float v = fmaxf(acc[t][n][j] * s + bias[n * 16 + l15], 0.f) * ps;
          Cb[(size_t)r * DD + n * 16 + l15] = f2fp8(v);
        }
      }
    }
  }
}

// Layer-2 GEMM with pooling fused into the epilogue: no feature output.
__global__ __launch_bounds__(256) void gemm_mfma_pool(
    const u16* __restrict__ Ab, const u16* __restrict__ Wt,
    const float* __restrict__ bias, const float* __restrict__ rs,
    const int* __restrict__ gid, float* __restrict__ pooled) {
  __shared__ float pl[NG * DD];  // 4 KB
  for (int i = threadIdx.x; i < NG * DD; i += 256) pl[i] = 0.f;
  GEMM_PRE
  float pacc[8];
#pragma unroll
  for (int n = 0; n < 8; ++n) pacc[n] = 0.f;
  int curg = -1;
#pragma unroll
  for (int t = 0; t < 2; ++t) {
    int crow0 = rowbase + t * 16 + kg * 4;
#pragma unroll
    for (int j = 0; j < 4; ++j) {
      int r = crow0 + j;
      if (r < NN) {
        int g = gid[r];
        if (g != curg) {
          if (curg >= 0) {
#pragma unroll
            for (int n = 0; n < 8; ++n) {
              atomicAdd(&pl[curg * DD + n * 16 + l15], pacc[n]);
              pacc[n] = 0.f;
            }
          }
          curg = g;
        }
        float s = rs[r];
#pragma unroll
        for (int n = 0; n < 8; ++n)
          pacc[n] += fmaxf(acc[t][n][j] * s + bias[n * 16 + l15], 0.f);
      }
    }
  }
  if (curg >= 0) {
#pragma unroll
    for (int n = 0; n < 8; ++n)
      atomicAdd(&pl[curg * DD + n * 16 + l15], pacc[n]);
  }
  __syncthreads();
  // gid sorted -> only graphs [gmin..gmax] touched by this block's 128 rows
  int rlo = blockIdx.x * 128;
  int rhi = rlo + 127;
  if (rhi >= NN) rhi = NN - 1;
  int gmin = gid[rlo];
  int gmax = gid[rhi];
  int span = (gmax - gmin + 1) * DD;
  for (int i = tid; i < span; i += 256) {
    float v = pl[gmin * DD + i];
    if (v != 0.f) atomicAdd(&pooled[gmin * DD + i], v);
  }
}

__global__ __launch_bounds__(128) void final_kernel(const float* __restrict__ pooled,
                                                    const int* __restrict__ cnt,
                                                    const float* __restrict__ prelu_a,
                                                    const float* __restrict__ linW,
                                                    const float* __restrict__ linb,
                                                    float* __restrict__ out) {
  int t = threadIdx.x;  // 128
  __shared__ float red[2];
  float w = linW[t];
  float alpha = prelu_a[0];
  float lb = linb[0];
  for (int g = 0; g < NG; ++g) {
    float v = pooled[g * DD + t] / fmaxf((float)cnt[g], 1.f);
    v = v > 0.f ? v : alpha * v;
    float p = v * w;
#pragma unroll
    for (int off = 32; off >= 1; off >>= 1) p += __shfl_down(p, off, 64);
    if ((t & 63) == 0) red[t >> 6] = p;
    __syncthreads();
    if (t == 0) {
      float s = red[0] + red[1] + lb;
      out[g] = 1.f / (1.f + expf(-s));
    }
    __syncthreads();
  }
}

extern "C" void kernel_launch(void* const* d_in, const int* in_sizes, int n_in,
                              void* d_out, int out_size, void* d_ws, size_t ws_size,
                              hipStream_t stream) {
  const float* x   = (const float*)d_in[0];
  const int*   src = (const int*)d_in[1];
  const int*   dst = (const int*)d_in[2];
  const int*   gid = (const int*)d_in[3];
  const float* W1  = (const float*)d_in[4];
  const float* b1  = (const float*)d_in[5];
  const float* W2  = (const float*)d_in[6];
  const float* b2  = (const float*)d_in[7];
  const float* pa  = (const float*)d_in[8];
  const float* lW  = (const float*)d_in[9];
  const float* lb  = (const float*)d_in[10];
  float* out = (float*)d_out;

  char* ws = (char*)d_ws;
  size_t o = 0;
  auto alloc = [&](size_t bytes) {
    size_t r = o;
    o += (bytes + 255) & ~(size_t)255;
    return r;
  };
  int*   deg_in  = (int*)(ws + alloc((size_t)NN * 4));
  float* rs_out  = (float*)(ws + alloc((size_t)NN * 4));
  float* rs_in   = (float*)(ws + alloc((size_t)NN * 4));
  int*   countsS = (int*)(ws + alloc((size_t)SCAN_N * 4));
  int*   countsD = (int*)(ws + alloc((size_t)SCAN_N * 4));
  int*   cursor_end = (int*)(ws + alloc((size_t)NN * 4));
  u16*   recsS   = (u16*)(ws + alloc((size_t)NE * 2));
  unsigned* recsD = (unsigned*)(ws + alloc((size_t)NE * 4));
  int*   csr_src = (int*)(ws + alloc((size_t)NE * 4));
  u16*   Wt1     = (u16*)(ws + alloc((size_t)DD * DD * 2));
  u16*   Wt2     = (u16*)(ws + alloc((size_t)DD * DD * 2));
  u8*    bufA    = (u8*)(ws + alloc((size_t)NN * DD));      // fp8 layer-1 input
  u8*    bufB    = (u8*)(ws + alloc((size_t)NN * DD));      // fp8 layer-2 input
  u16*   aggbuf  = (u16*)(ws + alloc((size_t)NN * DD * 2)); // bf16 agg
  float* pooled  = (float*)(ws + alloc((size_t)(NG * DD + NG) * 4));
  int*   cnt     = (int*)(pooled + NG * DD);

  fill_zero<<<2, 256, 0, stream>>>(pooled, (NG * DD + NG + 3) / 4);
  histo_gid<<<98, 256, 0, stream>>>(gid, cnt);

  // edge-array passes: bucket histograms -> scans -> record scatter
  p1_both<<<PB, 256, 0, stream>>>(src, dst, countsS, countsD);
  scan2<<<2, 256, 0, stream>>>(countsD, countsS);
  p2_both<<<PB, 256, 0, stream>>>(src, dst, countsS, countsD, recsS, recsD);
  src_p3<<<KB, 256, 0, stream>>>(recsS, countsS, rs_out);
  csr_p3<<<KB, 256, 0, stream>>>(recsD, countsD, csr_src, cursor_end, deg_in, rs_in);

  // x -> fp8 pre-scaled by rs_out; weights -> bf16 transposed
  conv_xscale<<<(NN * DD / 8 + 255) / 256, 256, 0, stream>>>(x, rs_out, bufA, NN * DD / 8);
  conv_w_transpose<<<64, 256, 0, stream>>>(W1, Wt1);
  conv_w_transpose<<<64, 256, 0, stream>>>(W2, Wt2);

  const int gablocks = (NN + 31) / 32;   // 3125
  const int gmblocks = (NN + 127) / 128; // 782

  // Layer 1: gather fp8 x-scaled; GEMM epilogue emits fp8 h1*rs_out
  gather_agg_fp8<<<gablocks, 256, 0, stream>>>((const uint4*)bufA, csr_src, cursor_end, deg_in, aggbuf);
  gemm_mfma_fp8out<<<gmblocks, 256, 0, stream>>>(aggbuf, Wt1, b1, rs_in, rs_out, bufB);

  // Layer 2: gather fp8, then GEMM with fused pooling
  gather_agg_fp8<<<gablocks, 256, 0, stream>>>((const uint4*)bufB, csr_src, cursor_end, deg_in, aggbuf);
  gemm_mfma_pool<<<gmblocks, 256, 0, stream>>>(aggbuf, Wt2, b2, rs_in, gid, pooled);

  // Head
  final_kernel<<<1, 128, 0, stream>>>(pooled, cnt, pa, lW, lb, out);
}

// Round 10
// 212.298 us; speedup vs baseline: 3.2981x; 1.1740x over previous
//
#include <hip/hip_runtime.h>
#include <hip/hip_bf16.h>

#define NN 100000
#define NE 1600000
#define DD 128
#define NG 8

#define BSH 8              // 256-node buckets
#define KB 391             // ceil(NN / 256)
#define BMASK 255
#define PB 512             // phase-1/2 blocks
#define CHUNK 3125         // NE / PB exactly
#define SCAN_N (KB * PB)

typedef unsigned short u16;
typedef unsigned char u8;
typedef __attribute__((ext_vector_type(8))) short short8;
typedef __attribute__((ext_vector_type(4))) float f32x4;
typedef __attribute__((ext_vector_type(2))) float f32x2;

static __device__ __forceinline__ float bf2f(u16 u) {
  return __uint_as_float(((unsigned)u) << 16);
}
static __device__ __forceinline__ u16 f2bf(float f) {
  unsigned u = __float_as_uint(f);
  u += 0x7fffu + ((u >> 16) & 1);
  return (u16)(u >> 16);
}
static __device__ __forceinline__ u8 f2fp8(float f) {
  return (u8)(__builtin_amdgcn_cvt_pk_fp8_f32(f, f, 0, false) & 0xFF);
}

__global__ void fill_zero(float* __restrict__ p, int n4) {
  int i = blockIdx.x * blockDim.x + threadIdx.x;
  if (i < n4) ((float4*)p)[i] = make_float4(0.f, 0.f, 0.f, 0.f);
}

// out[n][d] = fp8(x[n][d] * rs_out[n]); one thread = 8 elems -> 8 bytes
__global__ void conv_xscale(const float* __restrict__ in, const float* __restrict__ rs_out,
                            u8* __restrict__ out, int n8) {
  int i = blockIdx.x * blockDim.x + threadIdx.x;
  if (i >= n8) return;
  float w = rs_out[i >> 4];
  const float4* p = (const float4*)(in + (size_t)i * 8);
  float4 a = p[0], b = p[1];
  int lo = 0, hi = 0;
  lo = __builtin_amdgcn_cvt_pk_fp8_f32(a.x * w, a.y * w, lo, false);
  lo = __builtin_amdgcn_cvt_pk_fp8_f32(a.z * w, a.w * w, lo, true);
  hi = __builtin_amdgcn_cvt_pk_fp8_f32(b.x * w, b.y * w, hi, false);
  hi = __builtin_amdgcn_cvt_pk_fp8_f32(b.z * w, b.w * w, hi, true);
  ((uint2*)out)[i] = make_uint2((unsigned)lo, (unsigned)hi);
}

__global__ void conv_w_transpose(const float* __restrict__ W, u16* __restrict__ Wt) {
  int idx = blockIdx.x * blockDim.x + threadIdx.x;
  if (idx >= DD * DD) return;
  int n = idx >> 7, k = idx & 127;
  Wt[idx] = f2bf(W[k * DD + n]);
}

__global__ __launch_bounds__(256) void histo_gid(const int* __restrict__ gid,
                                                 int* __restrict__ cnt) {
  __shared__ int h[NG];
  int t = threadIdx.x;
  if (t < NG) h[t] = 0;
  __syncthreads();
  for (int i = blockIdx.x * 256 + t; i < NN; i += gridDim.x * 256)
    atomicAdd(&h[gid[i]], 1);
  __syncthreads();
  if (t < NG && h[t]) atomicAdd(&cnt[t], h[t]);
}

// ---- combined bucket histograms for src and dst ----
__global__ __launch_bounds__(256) void p1_both(const int* __restrict__ src,
                                               const int* __restrict__ dst,
                                               int* __restrict__ countsS,
                                               int* __restrict__ countsD) {
  __shared__ int hs[KB], hd[KB];
  int t = threadIdx.x, blk = blockIdx.x;
  for (int i = t; i < KB; i += 256) { hs[i] = 0; hd[i] = 0; }
  __syncthreads();
  int e0 = blk * CHUNK;
  for (int i = t; i < CHUNK; i += 256) {
    atomicAdd(&hs[src[e0 + i] >> BSH], 1);
    atomicAdd(&hd[dst[e0 + i] >> BSH], 1);
  }
  __syncthreads();
  for (int i = t; i < KB; i += 256) {
    countsS[i * PB + blk] = hs[i];
    countsD[i * PB + blk] = hd[i];
  }
}

// grid = 2*KB: per-bucket exclusive scan of its PB counts (in place), total out.
__global__ __launch_bounds__(256) void scanA(int* __restrict__ countsS,
                                             int* __restrict__ countsD,
                                             int* __restrict__ totS,
                                             int* __restrict__ totD) {
  __shared__ int data[PB];
  __shared__ int part[256];
  int b = blockIdx.x;
  int isS = (b < KB);
  int k = isS ? b : b - KB;
  int* counts = isS ? countsS : countsD;
  int* tot = isS ? totS : totD;
  int t = threadIdx.x;
  int* c = counts + (size_t)k * PB;
  data[t] = c[t];
  data[t + 256] = c[t + 256];
  __syncthreads();
  int a0 = data[2 * t], a1 = data[2 * t + 1];
  int s = a0 + a1;
  part[t] = s;
  __syncthreads();
  for (int off = 1; off < 256; off <<= 1) {
    int v = (t >= off) ? part[t - off] : 0;
    __syncthreads();
    part[t] += v;
    __syncthreads();
  }
  int ex = part[t] - s;
  data[2 * t] = ex;
  data[2 * t + 1] = ex + a0;
  __syncthreads();
  c[t] = data[t];
  c[t + 256] = data[t + 256];
  if (t == 255) tot[k] = part[255];
}

// grid = 2: exclusive scan of bucket totals -> base[KB+1]
__global__ __launch_bounds__(256) void scanB(const int* __restrict__ totS,
                                             const int* __restrict__ totD,
                                             int* __restrict__ baseS,
                                             int* __restrict__ baseD) {
  __shared__ int data[512];
  __shared__ int part[256];
  const int* tot = blockIdx.x ? totD : totS;
  int* base = blockIdx.x ? baseD : baseS;
  int t = threadIdx.x;
  data[t] = (t < KB) ? tot[t] : 0;
  data[t + 256] = (t + 256 < KB) ? tot[t + 256] : 0;
  __syncthreads();
  int a0 = data[2 * t], a1 = data[2 * t + 1];
  int s = a0 + a1;
  part[t] = s;
  __syncthreads();
  for (int off = 1; off < 256; off <<= 1) {
    int v = (t >= off) ? part[t - off] : 0;
    __syncthreads();
    part[t] += v;
    __syncthreads();
  }
  int ex = part[t] - s;
  int i0 = 2 * t, i1 = 2 * t + 1;
  if (i0 <= KB) base[i0] = ex;
  if (i1 <= KB) base[i1] = ex + a0;
}

// combined scatter: recsD (u32 CSR records) + recsS (u8 src low bits)
__global__ __launch_bounds__(256) void p2_both(const int* __restrict__ src,
                                               const int* __restrict__ dst,
                                               const int* __restrict__ countsS,
                                               const int* __restrict__ countsD,
                                               const int* __restrict__ baseS,
                                               const int* __restrict__ baseD,
                                               u8* __restrict__ recsS,
                                               unsigned* __restrict__ recsD) {
  __shared__ int curS[KB], curD[KB];
  int t = threadIdx.x, blk = blockIdx.x;
  for (int i = t; i < KB; i += 256) {
    curS[i] = countsS[i * PB + blk] + baseS[i];
    curD[i] = countsD[i * PB + blk] + baseD[i];
  }
  __syncthreads();
  int e0 = blk * CHUNK;
  for (int i = t; i < CHUNK; i += 256) {
    int s = src[e0 + i];
    int d = dst[e0 + i];
    int ps = atomicAdd(&curS[s >> BSH], 1);
    recsS[ps] = (u8)(s & BMASK);
    int pd = atomicAdd(&curD[d >> BSH], 1);
    recsD[pd] = (unsigned)s | ((unsigned)(d & BMASK) << 17);
  }
}

// per src-bucket histogram -> rs_out
__global__ __launch_bounds__(256) void src_p3(const u8* __restrict__ recsS,
                                              const int* __restrict__ baseS,
                                              float* __restrict__ rs_out) {
  __shared__ int hist[256];
  int k = blockIdx.x, t = threadIdx.x;
  int rbeg = baseS[k];
  int rend = baseS[k + 1];
  hist[t] = 0;
  __syncthreads();
  for (int i = rbeg + t; i < rend; i += 256) atomicAdd(&hist[recsS[i]], 1);
  __syncthreads();
  int n = (k << BSH) + t;
  if (n < NN) rs_out[n] = rsqrtf(fmaxf((float)hist[t], 1.f));
}

// One block per dst bucket: deg_in/rs_in/cursor_end + csr scatter.
__global__ __launch_bounds__(256) void csr_p3(const unsigned* __restrict__ recs,
                                              const int* __restrict__ baseD,
                                              int* __restrict__ csr_src,
                                              int* __restrict__ cursor_end,
                                              int* __restrict__ deg_in,
                                              float* __restrict__ rs_in) {
  __shared__ int hist[256];
  __shared__ int part[256];
  int k = blockIdx.x, t = threadIdx.x;
  int rbeg = baseD[k];
  int rend = baseD[k + 1];
  hist[t] = 0;
  __syncthreads();
  for (int i = rbeg + t; i < rend; i += 256) atomicAdd(&hist[recs[i] >> 17], 1);
  __syncthreads();
  int h = hist[t];
  part[t] = h;
  __syncthreads();
  for (int off = 1; off < 256; off <<= 1) {
    int v = (t >= off) ? part[t - off] : 0;
    __syncthreads();
    part[t] += v;
    __syncthreads();
  }
  int run = rbeg + part[t] - h;   // exclusive
  int n = (k << BSH) + t;
  if (n < NN) {
    cursor_end[n] = run + h;
    deg_in[n] = h;
    rs_in[n] = rsqrtf(fmaxf((float)h, 1.f));
  }
  hist[t] = run;
  __syncthreads();
  for (int i = rbeg + t; i < rend; i += 256) {
    unsigned r = recs[i];
    int pos = atomicAdd(&hist[r >> 17], 1);
    csr_src[pos] = (int)(r & 0x1FFFF);
  }
}

// One 8-lane group per dst node; lane q covers fp8 elems 16q..16q+15 (16B).
__global__ __launch_bounds__(256) void gather_agg_fp8(
    const uint4* __restrict__ Hv, const int* __restrict__ csr_src,
    const int* __restrict__ cursor_end, const int* __restrict__ deg_in,
    u16* __restrict__ agg) {
  int node = blockIdx.x * 32 + (threadIdx.x >> 3);
  if (node >= NN) return;
  int q = threadIdx.x & 7;
  int end = cursor_end[node];
  int j = end - deg_in[node];
  float acc[16];
#pragma unroll
  for (int i = 0; i < 16; ++i) acc[i] = 0.f;
#define ACCV(v) { f32x2 t_;                                                        \
  t_ = __builtin_amdgcn_cvt_pk_f32_fp8((int)(v).x, false); acc[0] += t_.x;  acc[1] += t_.y;  \
  t_ = __builtin_amdgcn_cvt_pk_f32_fp8((int)(v).x, true);  acc[2] += t_.x;  acc[3] += t_.y;  \
  t_ = __builtin_amdgcn_cvt_pk_f32_fp8((int)(v).y, false); acc[4] += t_.x;  acc[5] += t_.y;  \
  t_ = __builtin_amdgcn_cvt_pk_f32_fp8((int)(v).y, true);  acc[6] += t_.x;  acc[7] += t_.y;  \
  t_ = __builtin_amdgcn_cvt_pk_f32_fp8((int)(v).z, false); acc[8] += t_.x;  acc[9] += t_.y;  \
  t_ = __builtin_amdgcn_cvt_pk_f32_fp8((int)(v).z, true);  acc[10] += t_.x; acc[11] += t_.y; \
  t_ = __builtin_amdgcn_cvt_pk_f32_fp8((int)(v).w, false); acc[12] += t_.x; acc[13] += t_.y; \
  t_ = __builtin_amdgcn_cvt_pk_f32_fp8((int)(v).w, true);  acc[14] += t_.x; acc[15] += t_.y; }
  for (; j + 4 <= end; j += 4) {
    int s0 = csr_src[j + 0];
    int s1 = csr_src[j + 1];
    int s2 = csr_src[j + 2];
    int s3 = csr_src[j + 3];
    uint4 v0 = Hv[(size_t)s0 * 8 + q];
    uint4 v1 = Hv[(size_t)s1 * 8 + q];
    uint4 v2 = Hv[(size_t)s2 * 8 + q];
    uint4 v3 = Hv[(size_t)s3 * 8 + q];
    ACCV(v0) ACCV(v1) ACCV(v2) ACCV(v3)
  }
  for (; j < end; ++j) {
    uint4 v = Hv[(size_t)csr_src[j] * 8 + q];
    ACCV(v)
  }
#undef ACCV
  uint4 o0, o1;
  o0.x = (unsigned)f2bf(acc[0])  | ((unsigned)f2bf(acc[1])  << 16);
  o0.y = (unsigned)f2bf(acc[2])  | ((unsigned)f2bf(acc[3])  << 16);
  o0.z = (unsigned)f2bf(acc[4])  | ((unsigned)f2bf(acc[5])  << 16);
  o0.w = (unsigned)f2bf(acc[6])  | ((unsigned)f2bf(acc[7])  << 16);
  o1.x = (unsigned)f2bf(acc[8])  | ((unsigned)f2bf(acc[9])  << 16);
  o1.y = (unsigned)f2bf(acc[10]) | ((unsigned)f2bf(acc[11]) << 16);
  o1.z = (unsigned)f2bf(acc[12]) | ((unsigned)f2bf(acc[13]) << 16);
  o1.w = (unsigned)f2bf(acc[14]) | ((unsigned)f2bf(acc[15]) << 16);
  u16* op = agg + (size_t)node * DD + q * 16;
  *(uint4*)op = o0;
  *(uint4*)(op + 8) = o1;
}

// ---- LDS-staged GEMM core ----
#define GEMM_PRE                                                              \
  __shared__ uint4 Wl4[2048]; /* 32 KB */                                     \
  int tid = threadIdx.x;                                                      \
  {                                                                           \
    const uint4* Wg4 = (const uint4*)Wt;                                      \
    for (int i = tid; i < 2048; i += 256) {                                   \
      int row = i >> 4, c = i & 15;                                           \
      Wl4[(row << 4) | (c ^ (row & 15))] = Wg4[i];                            \
    }                                                                         \
  }                                                                           \
  int wid = tid >> 6;                                                         \
  int lane = tid & 63;                                                        \
  int l15 = lane & 15;                                                        \
  int kg = lane >> 4;                                                         \
  int rowbase = blockIdx.x * 128 + wid * 32;                                  \
  f32x4 acc[2][8];                                                            \
  short8 a[2][4];                                                             \
  _Pragma("unroll")                                                           \
  for (int t = 0; t < 2; ++t) {                                               \
    int arow = rowbase + t * 16 + l15;                                        \
    bool ok = arow < NN;                                                      \
    const u16* aptr = Ab + (size_t)arow * DD + kg * 8;                        \
    _Pragma("unroll")                                                         \
    for (int kt = 0; kt < 4; ++kt) {                                          \
      a[t][kt] = ok ? *(const short8*)(aptr + kt * 32)                        \
                    : (short8){0, 0, 0, 0, 0, 0, 0, 0};                       \
      acc[0][kt] = (f32x4){0.f, 0.f, 0.f, 0.f};                               \
      acc[0][kt + 4] = (f32x4){0.f, 0.f, 0.f, 0.f};                           \
      acc[1][kt] = (f32x4){0.f, 0.f, 0.f, 0.f};                               \
      acc[1][kt + 4] = (f32x4){0.f, 0.f, 0.f, 0.f};                           \
    }                                                                         \
  }                                                                           \
  __syncthreads();                                                            \
  _Pragma("unroll")                                                           \
  for (int n = 0; n < 8; ++n) {                                               \
    _Pragma("unroll")                                                         \
    for (int kt = 0; kt < 4; ++kt) {                                          \
      short8 b = *(const short8*)(Wl4 + (((n * 16 + l15) << 4) |              \
                                         ((kg + kt * 4) ^ l15)));             \
      acc[0][n] = __builtin_amdgcn_mfma_f32_16x16x32_bf16(a[0][kt], b, acc[0][n], 0, 0, 0); \
      acc[1][n] = __builtin_amdgcn_mfma_f32_16x16x32_bf16(a[1][kt], b, acc[1][n], 0, 0, 0); \
    }                                                                         \
  }

// C = fp8( relu((A@W)*rs + bias) * post ), byte out.
__global__ __launch_bounds__(256) void gemm_mfma_fp8out(
    const u16* __restrict__ Ab, const u16* __restrict__ Wt,
    const float* __restrict__ bias, const float* __restrict__ rs,
    const float* __restrict__ post, u8* __restrict__ Cb) {
  GEMM_PRE
#pragma unroll
  for (int t = 0; t < 2; ++t) {
    int crow0 = rowbase + t * 16 + kg * 4;
#pragma unroll
    for (int j = 0; j < 4; ++j) {
      int r = crow0 + j;
      if (r < NN) {
        float s = rs[r];
        float ps = post[r];
#pragma unroll
        for (int n = 0; n < 8; ++n) {
          float v = fmaxf(acc[t][n][j] * s + bias[n * 16 + l15], 0.f) * ps;
          Cb[(size_t)r * DD + n * 16 + l15] = f2fp8(v);
        }
      }
    }
  }
}

// Layer-2 GEMM with pooling fused into the epilogue: no feature output.
__global__ __launch_bounds__(256) void gemm_mfma_pool(
    const u16* __restrict__ Ab, const u16* __restrict__ Wt,
    const float* __restrict__ bias, const float* __restrict__ rs,
    const int* __restrict__ gid, float* __restrict__ pooled) {
  __shared__ float pl[NG * DD];  // 4 KB
  for (int i = threadIdx.x; i < NG * DD; i += 256) pl[i] = 0.f;
  GEMM_PRE
  float pacc[8];
#pragma unroll
  for (int n = 0; n < 8; ++n) pacc[n] = 0.f;
  int curg = -1;
#pragma unroll
  for (int t = 0; t < 2; ++t) {
    int crow0 = rowbase + t * 16 + kg * 4;
#pragma unroll
    for (int j = 0; j < 4; ++j) {
      int r = crow0 + j;
      if (r < NN) {
        int g = gid[r];
        if (g != curg) {
          if (curg >= 0) {
#pragma unroll
            for (int n = 0; n < 8; ++n) {
              atomicAdd(&pl[curg * DD + n * 16 + l15], pacc[n]);
              pacc[n] = 0.f;
            }
          }
          curg = g;
        }
        float s = rs[r];
#pragma unroll
        for (int n = 0; n < 8; ++n)
          pacc[n] += fmaxf(acc[t][n][j] * s + bias[n * 16 + l15], 0.f);
      }
    }
  }
  if (curg >= 0) {
#pragma unroll
    for (int n = 0; n < 8; ++n)
      atomicAdd(&pl[curg * DD + n * 16 + l15], pacc[n]);
  }
  __syncthreads();
  int rlo = blockIdx.x * 128;
  int rhi = rlo + 127;
  if (rhi >= NN) rhi = NN - 1;
  int gmin = gid[rlo];
  int gmax = gid[rhi];
  int span = (gmax - gmin + 1) * DD;
  for (int i = tid; i < span; i += 256) {
    float v = pl[gmin * DD + i];
    if (v != 0.f) atomicAdd(&pooled[gmin * DD + i], v);
  }
}

__global__ __launch_bounds__(128) void final_kernel(const float* __restrict__ pooled,
                                                    const int* __restrict__ cnt,
                                                    const float* __restrict__ prelu_a,
                                                    const float* __restrict__ linW,
                                                    const float* __restrict__ linb,
                                                    float* __restrict__ out) {
  int t = threadIdx.x;  // 128
  __shared__ float red[2];
  float w = linW[t];
  float alpha = prelu_a[0];
  float lb = linb[0];
  for (int g = 0; g < NG; ++g) {
    float v = pooled[g * DD + t] / fmaxf((float)cnt[g], 1.f);
    v = v > 0.f ? v : alpha * v;
    float p = v * w;
#pragma unroll
    for (int off = 32; off >= 1; off >>= 1) p += __shfl_down(p, off, 64);
    if ((t & 63) == 0) red[t >> 6] = p;
    __syncthreads();
    if (t == 0) {
      float s = red[0] + red[1] + lb;
      out[g] = 1.f / (1.f + expf(-s));
    }
    __syncthreads();
  }
}

extern "C" void kernel_launch(void* const* d_in, const int* in_sizes, int n_in,
                              void* d_out, int out_size, void* d_ws, size_t ws_size,
                              hipStream_t stream) {
  const float* x   = (const float*)d_in[0];
  const int*   src = (const int*)d_in[1];
  const int*   dst = (const int*)d_in[2];
  const int*   gid = (const int*)d_in[3];
  const float* W1  = (const float*)d_in[4];
  const float* b1  = (const float*)d_in[5];
  const float* W2  = (const float*)d_in[6];
  const float* b2  = (const float*)d_in[7];
  const float* pa  = (const float*)d_in[8];
  const float* lW  = (const float*)d_in[9];
  const float* lb  = (const float*)d_in[10];
  float* out = (float*)d_out;

  char* ws = (char*)d_ws;
  size_t o = 0;
  auto alloc = [&](size_t bytes) {
    size_t r = o;
    o += (bytes + 255) & ~(size_t)255;
    return r;
  };
  int*   deg_in  = (int*)(ws + alloc((size_t)NN * 4));
  float* rs_out  = (float*)(ws + alloc((size_t)NN * 4));
  float* rs_in   = (float*)(ws + alloc((size_t)NN * 4));
  int*   countsS = (int*)(ws + alloc((size_t)SCAN_N * 4));
  int*   countsD = (int*)(ws + alloc((size_t)SCAN_N * 4));
  int*   totS    = (int*)(ws + alloc((size_t)KB * 4));
  int*   totD    = (int*)(ws + alloc((size_t)KB * 4));
  int*   baseS   = (int*)(ws + alloc((size_t)(KB + 1) * 4));
  int*   baseD   = (int*)(ws + alloc((size_t)(KB + 1) * 4));
  int*   cursor_end = (int*)(ws + alloc((size_t)NN * 4));
  u8*    recsS   = (u8*)(ws + alloc((size_t)NE));
  unsigned* recsD = (unsigned*)(ws + alloc((size_t)NE * 4));
  int*   csr_src = (int*)(ws + alloc((size_t)NE * 4));
  u16*   Wt1     = (u16*)(ws + alloc((size_t)DD * DD * 2));
  u16*   Wt2     = (u16*)(ws + alloc((size_t)DD * DD * 2));
  u8*    bufA    = (u8*)(ws + alloc((size_t)NN * DD));      // fp8 layer-1 input
  u8*    bufB    = (u8*)(ws + alloc((size_t)NN * DD));      // fp8 layer-2 input
  u16*   aggbuf  = (u16*)(ws + alloc((size_t)NN * DD * 2)); // bf16 agg
  float* pooled  = (float*)(ws + alloc((size_t)(NG * DD + NG) * 4));
  int*   cnt     = (int*)(pooled + NG * DD);

  fill_zero<<<2, 256, 0, stream>>>(pooled, (NG * DD + NG + 3) / 4);
  histo_gid<<<98, 256, 0, stream>>>(gid, cnt);

  // edge-array passes: bucket histograms -> 2-level scans -> record scatter
  p1_both<<<PB, 256, 0, stream>>>(src, dst, countsS, countsD);
  scanA<<<2 * KB, 256, 0, stream>>>(countsS, countsD, totS, totD);
  scanB<<<2, 256, 0, stream>>>(totS, totD, baseS, baseD);
  p2_both<<<PB, 256, 0, stream>>>(src, dst, countsS, countsD, baseS, baseD, recsS, recsD);
  src_p3<<<KB, 256, 0, stream>>>(recsS, baseS, rs_out);
  csr_p3<<<KB, 256, 0, stream>>>(recsD, baseD, csr_src, cursor_end, deg_in, rs_in);

  // x -> fp8 pre-scaled by rs_out; weights -> bf16 transposed
  conv_xscale<<<(NN * DD / 8 + 255) / 256, 256, 0, stream>>>(x, rs_out, bufA, NN * DD / 8);
  conv_w_transpose<<<64, 256, 0, stream>>>(W1, Wt1);
  conv_w_transpose<<<64, 256, 0, stream>>>(W2, Wt2);

  const int gablocks = (NN + 31) / 32;   // 3125
  const int gmblocks = (NN + 127) / 128; // 782

  // Layer 1: gather fp8 x-scaled; GEMM epilogue emits fp8 h1*rs_out
  gather_agg_fp8<<<gablocks, 256, 0, stream>>>((const uint4*)bufA, csr_src, cursor_end, deg_in, aggbuf);
  gemm_mfma_fp8out<<<gmblocks, 256, 0, stream>>>(aggbuf, Wt1, b1, rs_in, rs_out, bufB);

  // Layer 2: gather fp8, then GEMM with fused pooling
  gather_agg_fp8<<<gablocks, 256, 0, stream>>>((const uint4*)bufB, csr_src, cursor_end, deg_in, aggbuf);
  gemm_mfma_pool<<<gmblocks, 256, 0, stream>>>(aggbuf, Wt2, b2, rs_in, gid, pooled);

  // Head
  final_kernel<<<1, 128, 0, stream>>>(pooled, cnt, pa, lW, lb, out);
}